// Round 11
// baseline (475.602 us; speedup 1.0000x reference)
//
#include <hip/hip_runtime.h>

typedef __attribute__((ext_vector_type(8))) unsigned short us8;
typedef __attribute__((ext_vector_type(4))) unsigned short us4;
typedef __attribute__((ext_vector_type(8))) short bf16x8;
typedef __attribute__((ext_vector_type(4))) float f32x4;

#define LMASK 16383
#define SQRT_C 22.627416997969522f
#define LOGIT_MAXV 4.605170185988091f

__device__ __forceinline__ float bf2f(unsigned short u) {
  unsigned int x = ((unsigned int)u) << 16;
  return __builtin_bit_cast(float, x);
}
__device__ __forceinline__ unsigned short f2bf(float f) {
  unsigned int x = __builtin_bit_cast(unsigned int, f);
  x = x + 0x7FFFu + ((x >> 16) & 1u);
  return (unsigned short)(x >> 16);
}
__device__ __forceinline__ void gload16(const void* g, void* lds) {
  __builtin_amdgcn_global_load_lds(
      (const __attribute__((address_space(1))) unsigned int*)g,
      (__attribute__((address_space(3))) unsigned int*)lds, 16, 0, 0);
}

// ---------------- prep kernels ----------------
__global__ void cvt8_k(const float* __restrict__ src, unsigned short* __restrict__ dst, int n8) {
  int idx = blockIdx.x * 256 + threadIdx.x;
  if (idx >= n8) return;
  const float* s = src + (long)idx * 8;
  us8 u;
  #pragma unroll
  for (int e = 0; e < 8; ++e) u[e] = f2bf(s[e]);
  *(us8*)(dst + (long)idx * 8) = u;
}

__global__ void rollcvt_k(const float* __restrict__ x, unsigned short* __restrict__ xb) {
  long e = ((long)blockIdx.x * 256 + threadIdx.x) * 8;
  long row = e >> 9;
  int col = (int)(e & 511);
  long src = ((row >> 14) << 14) | (((row & LMASK) + 64) & LMASK);
  const float* s = x + src * 512 + col;
  us8 u;
  #pragma unroll
  for (int ee = 0; ee < 8; ++ee) u[ee] = f2bf(s[ee]);
  *(us8*)(xb + e) = u;
}

__global__ __launch_bounds__(256) void cpb_k(const float* __restrict__ w1,
    const float* __restrict__ b1, const float* __restrict__ w2,
    float* __restrict__ sig_tbl) {
  __shared__ float hbuf[512];
  const int i = blockIdx.x;
  const int tid = threadIdx.x;
  const float t = (float)(i - 127) * (8.f / 127.f);
  const float sgn = (t < 0.f) ? -1.f : 1.f;
  const float s = sgn * (log2f(fabsf(t) + 1.f) * (1.f / 3.f));
  hbuf[tid]       = fmaxf(s * w1[tid] + b1[tid], 0.f);
  hbuf[tid + 256] = fmaxf(s * w1[tid + 256] + b1[tid + 256], 0.f);
  __syncthreads();
  const int wv = tid >> 6, lane = tid & 63;
  for (int q = 0; q < 4; ++q) {
    const int n = wv * 4 + q;
    float part = 0.f;
    for (int c = lane; c < 512; c += 64) part += hbuf[c] * w2[n * 512 + c];
    #pragma unroll
    for (int o = 1; o < 64; o <<= 1) part += __shfl_xor(part, o);
    if (lane == 0) sig_tbl[i * 16 + n] = 16.f / (1.f + expf(-part));
  }
}

__global__ void qkvbias_k(const float* __restrict__ qb, const float* __restrict__ vb,
                          float* __restrict__ ob) {
  const int n = blockIdx.x * 256 + threadIdx.x;
  float v = 0.f;
  if (n < 512) v = qb[n];
  else if (n >= 1024) v = vb[n - 1024];
  ob[n] = v;
}

// ====== pipelined gemmS: 128x128, BK=32, 4 waves, triple-buffer (48 KB) ======
// Depth-2 counted-vmcnt prefetch; ONE raw barrier per K-step; NO sched_barrier,
// NO setprio — compiler free to schedule ds_read/MFMA/stage-issue.
// Per iter: vmcnt(4) [stage(t) done, stage(t+1) in flight] -> s_barrier ->
//           issue stage(t+2) into buf (t-1)%3 -> frags+MFMA.
// WAR safe: all reads of buf (t-1)%3 were lgkm-consumed before this barrier.
template<int NY, int EPI>
__device__ __forceinline__ void gemmS_body(
    const unsigned short* __restrict__ Ab, const unsigned short* __restrict__ Bw,
    const float* __restrict__ bias, unsigned short* __restrict__ outb, int K) {
  __shared__ unsigned short As[3][128 * 32];
  __shared__ unsigned short Bs[3][128 * 32];
  const int N = NY * 128;
  const int tid = threadIdx.x;
  const int w = tid >> 6, l = tid & 63;
  const int wrow = w >> 1, wcol = w & 1;
  const int nwg = gridDim.x;
  const int id = blockIdx.x;
  const int lid = (id & 7) * (nwg >> 3) + (id >> 3);
  const int mi = lid / NY, ni = lid - mi * NY;
  const int m0 = mi * 128, n0 = ni * 128;
  const int lr = l & 15, lh = l >> 4;
  f32x4 acc[4][4];
  #pragma unroll
  for (int m = 0; m < 4; ++m)
    #pragma unroll
    for (int n = 0; n < 4; ++n) acc[m][n] = (f32x4)0.f;
  const int fsw = (lr >> 1) & 3;
  int aoff[4], boff[4];
  #pragma unroll
  for (int m = 0; m < 4; ++m)
    aoff[m] = (wrow * 64 + m * 16 + lr) * 64 + ((lh ^ fsw) << 4);
  #pragma unroll
  for (int n = 0; n < 4; ++n)
    boff[n] = (wcol * 64 + n * 16 + lr) * 64 + ((lh ^ fsw) << 4);
  const int srow = l >> 2;
  const int schunk = (l & 3) ^ ((srow >> 1) & 3);
  const int NT = K >> 5;

  auto stage = [&](int kt, int bi) {
    const int k0 = kt << 5;
    gload16(Ab + (long)(m0 + w * 16 + srow) * K + k0 + schunk * 8, (char*)As[bi] + w * 1024);
    gload16(Ab + (long)(m0 + 64 + w * 16 + srow) * K + k0 + schunk * 8,
            (char*)As[bi] + 4096 + w * 1024);
    gload16(Bw + (long)(n0 + w * 16 + srow) * K + k0 + schunk * 8, (char*)Bs[bi] + w * 1024);
    gload16(Bw + (long)(n0 + 64 + w * 16 + srow) * K + k0 + schunk * 8,
            (char*)Bs[bi] + 4096 + w * 1024);
  };

  stage(0, 0);
  stage(1, 1);

  int bi = 0;
  for (int t = 0; t < NT; ++t) {
    if (t + 1 < NT) { asm volatile("s_waitcnt vmcnt(4)" ::: "memory"); }
    else            { asm volatile("s_waitcnt vmcnt(0)" ::: "memory"); }
    __builtin_amdgcn_s_barrier();
    if (t + 2 < NT) stage(t + 2, (bi + 2 >= 3) ? bi - 1 : bi + 2);
    bf16x8 a[4], b[4];
    #pragma unroll
    for (int m = 0; m < 4; ++m) a[m] = *(const bf16x8*)((const char*)As[bi] + aoff[m]);
    #pragma unroll
    for (int n = 0; n < 4; ++n) b[n] = *(const bf16x8*)((const char*)Bs[bi] + boff[n]);
    #pragma unroll
    for (int m = 0; m < 4; ++m)
      #pragma unroll
      for (int n = 0; n < 4; ++n)
        acc[m][n] = __builtin_amdgcn_mfma_f32_16x16x32_bf16(a[m], b[n], acc[m][n], 0, 0, 0);
    bi = (bi + 1 == 3) ? 0 : bi + 1;
  }

  float bv[4];
  #pragma unroll
  for (int n = 0; n < 4; ++n) bv[n] = bias[n0 + wcol * 64 + n * 16 + lr];
  #pragma unroll
  for (int m = 0; m < 4; ++m)
    #pragma unroll
    for (int reg = 0; reg < 4; ++reg) {
      const long row = m0 + wrow * 64 + m * 16 + lh * 4 + reg;
      #pragma unroll
      for (int n = 0; n < 4; ++n) {
        const int col = n0 + wcol * 64 + n * 16 + lr;
        float v = acc[m][n][reg] + bv[n];
        if constexpr (EPI == 3) v = v / (1.f + __expf(-v));
        outb[row * (long)N + col] = f2bf(v);
      }
    }
}

__global__ __launch_bounds__(256) void qkv_gemm(
    const unsigned short* __restrict__ A, const unsigned short* __restrict__ B,
    const float* __restrict__ bias, unsigned short* __restrict__ C) {
  gemmS_body<12, 2>(A, B, bias, C, 512);
}
__global__ __launch_bounds__(256) void proj_gemm(
    const unsigned short* __restrict__ A, const unsigned short* __restrict__ B,
    const float* __restrict__ bias, unsigned short* __restrict__ C) {
  gemmS_body<4, 2>(A, B, bias, C, 512);
}
__global__ __launch_bounds__(256) void mlp1_gemm(
    const unsigned short* __restrict__ A, const unsigned short* __restrict__ B,
    const float* __restrict__ bias, unsigned short* __restrict__ C) {
  gemmS_body<16, 3>(A, B, bias, C, 512);
}
__global__ __launch_bounds__(256) void mlp2_gemm(
    const unsigned short* __restrict__ A, const unsigned short* __restrict__ B,
    const float* __restrict__ bias, unsigned short* __restrict__ C) {
  gemmS_body<4, 2>(A, B, bias, C, 2048);
}

// ---- addnorm1: out[dest]=x[dest]+rms(y[r])*nw (f32) AND x1b[dest]=bf16(out) ----
__global__ __launch_bounds__(128) void addnorm_roll_k(const unsigned short* __restrict__ y,
    const float* __restrict__ x, const float* __restrict__ nw, float* __restrict__ out,
    unsigned short* __restrict__ x1b) {
  const int r = blockIdx.x;
  const int tid = threadIdx.x;
  us4 u = *(const us4*)(y + (long)r * 512 + tid * 4);
  float v0 = bf2f(u[0]), v1 = bf2f(u[1]), v2 = bf2f(u[2]), v3 = bf2f(u[3]);
  float ss = v0 * v0 + v1 * v1 + v2 * v2 + v3 * v3;
  #pragma unroll
  for (int o = 1; o < 64; o <<= 1) ss += __shfl_xor(ss, o);
  __shared__ float tot[2];
  if ((tid & 63) == 0) tot[tid >> 6] = ss;
  __syncthreads();
  const float inv = SQRT_C * rsqrtf((tot[0] + tot[1]) * (1.f / 512.f) + 1e-8f);
  const long dest = ((long)(r >> 14) << 14) | (((r & LMASK) + 64) & LMASK);
  float4 wv = *(const float4*)(nw + tid * 4);
  float4 xv = *(const float4*)(x + dest * 512 + tid * 4);
  float4 o4;
  o4.x = xv.x + v0 * inv * wv.x;
  o4.y = xv.y + v1 * inv * wv.y;
  o4.z = xv.z + v2 * inv * wv.z;
  o4.w = xv.w + v3 * inv * wv.w;
  *(float4*)(out + dest * 512 + tid * 4) = o4;
  us4 ub;
  ub[0] = f2bf(o4.x); ub[1] = f2bf(o4.y); ub[2] = f2bf(o4.z); ub[3] = f2bf(o4.w);
  *(us4*)(x1b + dest * 512 + tid * 4) = ub;
}

// ---- addnorm2: out[r0+r] += rms(y[r])*nw (in place on d_out) ----
__global__ __launch_bounds__(128) void addnorm_final_k(const unsigned short* __restrict__ y,
    const float* __restrict__ nw, float* __restrict__ out, int r0) {
  const int r = blockIdx.x;
  const int tid = threadIdx.x;
  us4 u = *(const us4*)(y + (long)r * 512 + tid * 4);
  float v0 = bf2f(u[0]), v1 = bf2f(u[1]), v2 = bf2f(u[2]), v3 = bf2f(u[3]);
  float ss = v0 * v0 + v1 * v1 + v2 * v2 + v3 * v3;
  #pragma unroll
  for (int o = 1; o < 64; o <<= 1) ss += __shfl_xor(ss, o);
  __shared__ float tot[2];
  if ((tid & 63) == 0) tot[tid >> 6] = ss;
  __syncthreads();
  const float inv = SQRT_C * rsqrtf((tot[0] + tot[1]) * (1.f / 512.f) + 1e-8f);
  const long base = (long)(r0 + r) * 512 + tid * 4;
  float4 wv = *(const float4*)(nw + tid * 4);
  float4 xv = *(const float4*)(out + base);
  float4 o4;
  o4.x = xv.x + v0 * inv * wv.x;
  o4.y = xv.y + v1 * inv * wv.y;
  o4.z = xv.z + v2 * inv * wv.z;
  o4.w = xv.w + v3 * inv * wv.w;
  *(float4*)(out + base) = o4;
}

// ---------------- attention via MFMA: one block per (head, window) ----------------
__global__ __launch_bounds__(256, 2) void attn_k(const unsigned short* __restrict__ qkv,
    const float* __restrict__ logit_scale, const float* __restrict__ sig_tbl,
    unsigned short* __restrict__ attnout) {
  __shared__ unsigned short qs[128 * 32];
  __shared__ unsigned short ks[128 * 32];
  __shared__ unsigned short vt[32 * 136];
  __shared__ unsigned short ps[128 * 136];
  __shared__ float qinv[128], kinv[128], lbias[256];
  const int h = blockIdx.x, w = blockIdx.y;
  const int tid = threadIdx.x;
  const int wv = tid >> 6, l = tid & 63;
  const int lr = l & 15, quad = l >> 4;

  {
    const int srow = l >> 2;
    const int cs = (l & 3) ^ ((srow >> 1) & 3);
    #pragma unroll
    for (int rnd = 0; rnd < 2; ++rnd) {
      const int row = wv * 32 + rnd * 16 + srow;
      const long gb = (long)(w * 128 + row) * 1536 + h * 32 + cs * 8;
      gload16(qkv + gb, (char*)qs + (wv * 32 + rnd * 16) * 64);
      gload16(qkv + gb + 512, (char*)ks + (wv * 32 + rnd * 16) * 64);
    }
  }
  #pragma unroll
  for (int rnd = 0; rnd < 2; ++rnd) {
    const int j = wv * 32 + rnd * 16 + (l >> 2);
    const int d0 = (l & 3) * 8;
    us8 uv = *(const us8*)(qkv + (long)(w * 128 + j) * 1536 + h * 32 + 1024 + d0);
    #pragma unroll
    for (int e = 0; e < 8; ++e) vt[(d0 + e) * 136 + j] = uv[e];
  }
  if (tid < 255) lbias[tid] = sig_tbl[tid * 16 + h];
  __syncthreads();

  const float scale = __expf(fminf(logit_scale[h], LOGIT_MAXV));
  {
    const int r = tid >> 1, cp = tid & 1;
    const int sw = (r >> 1) & 3;
    float sq = 0.f, sk = 0.f;
    #pragma unroll
    for (int cc = 0; cc < 2; ++cc) {
      const int slot = (cp * 2 + cc) ^ sw;
      us8 uq = *(const us8*)(qs + r * 32 + slot * 8);
      us8 uk = *(const us8*)(ks + r * 32 + slot * 8);
      #pragma unroll
      for (int e = 0; e < 8; ++e) {
        float fq = bf2f(uq[e]), fk = bf2f(uk[e]);
        sq = fmaf(fq, fq, sq);
        sk = fmaf(fk, fk, sk);
      }
    }
    sq += __shfl_xor(sq, 1);
    sk += __shfl_xor(sk, 1);
    qinv[r] = scale / fmaxf(sqrtf(sq), 1e-12f);
    kinv[r] = 1.f / fmaxf(sqrtf(sk), 1e-12f);
  }
  __syncthreads();

  const int fsw = (lr >> 1) & 3;
  bf16x8 aq[2];
  #pragma unroll
  for (int mt = 0; mt < 2; ++mt)
    aq[mt] = *(const bf16x8*)((const char*)qs + (wv * 32 + mt * 16 + lr) * 64 + ((quad ^ fsw) << 4));
  f32x4 s[2][8];
  #pragma unroll
  for (int nt = 0; nt < 8; ++nt) {
    bf16x8 bk = *(const bf16x8*)((const char*)ks + (nt * 16 + lr) * 64 + ((quad ^ fsw) << 4));
    #pragma unroll
    for (int mt = 0; mt < 2; ++mt)
      s[mt][nt] = __builtin_amdgcn_mfma_f32_16x16x32_bf16(aq[mt], bk, (f32x4)0.f, 0, 0, 0);
  }

  float kv8[8];
  #pragma unroll
  for (int nt = 0; nt < 8; ++nt) kv8[nt] = kinv[nt * 16 + lr];
  const bool lastwin = ((w & 127) == 127);
  const bool ihalf = (wv < 2);
  float sum[2][4];
  #pragma unroll
  for (int mt = 0; mt < 2; ++mt) {
    #pragma unroll
    for (int reg = 0; reg < 4; ++reg) {
      const int row = wv * 32 + mt * 16 + quad * 4 + reg;
      const float qv = qinv[row];
      const int bb = row + 127 - lr;
      float m = -1e30f;
      #pragma unroll
      for (int nt = 0; nt < 8; ++nt) {
        float v = s[mt][nt][reg] * qv * kv8[nt] + lbias[bb - nt * 16];
        if (lastwin && (ihalf != (nt < 4))) v -= 100.f;
        s[mt][nt][reg] = v;
        m = fmaxf(m, v);
      }
      m = fmaxf(m, __shfl_xor(m, 1));
      m = fmaxf(m, __shfl_xor(m, 2));
      m = fmaxf(m, __shfl_xor(m, 4));
      m = fmaxf(m, __shfl_xor(m, 8));
      float sm = 0.f;
      #pragma unroll
      for (int nt = 0; nt < 8; ++nt) {
        float p = __expf(s[mt][nt][reg] - m);
        s[mt][nt][reg] = p;
        sm += p;
      }
      sm += __shfl_xor(sm, 1);
      sm += __shfl_xor(sm, 2);
      sm += __shfl_xor(sm, 4);
      sm += __shfl_xor(sm, 8);
      sum[mt][reg] = sm;
      #pragma unroll
      for (int nt = 0; nt < 8; ++nt)
        ps[row * 136 + nt * 16 + lr] = f2bf(s[mt][nt][reg]);
    }
  }
  __syncthreads();

  f32x4 o[2][2];
  #pragma unroll
  for (int mt = 0; mt < 2; ++mt)
    #pragma unroll
    for (int nt = 0; nt < 2; ++nt) o[mt][nt] = (f32x4)0.f;
  #pragma unroll
  for (int kt = 0; kt < 4; ++kt) {
    bf16x8 pa[2], vb[2];
    #pragma unroll
    for (int mt = 0; mt < 2; ++mt)
      pa[mt] = *(const bf16x8*)((const char*)ps + (wv * 32 + mt * 16 + lr) * 272 + (kt * 4 + quad) * 16);
    #pragma unroll
    for (int nt = 0; nt < 2; ++nt)
      vb[nt] = *(const bf16x8*)((const char*)vt + (nt * 16 + lr) * 272 + (kt * 4 + quad) * 16);
    #pragma unroll
    for (int mt = 0; mt < 2; ++mt)
      #pragma unroll
      for (int nt = 0; nt < 2; ++nt)
        o[mt][nt] = __builtin_amdgcn_mfma_f32_16x16x32_bf16(pa[mt], vb[nt], o[mt][nt], 0, 0, 0);
  }
  #pragma unroll
  for (int mt = 0; mt < 2; ++mt) {
    #pragma unroll
    for (int reg = 0; reg < 4; ++reg) {
      const int row = wv * 32 + mt * 16 + quad * 4 + reg;
      const float si = 1.f / sum[mt][reg];
      const long ob = (long)(w * 128 + row) * 512 + h * 32;
      attnout[ob + lr]      = f2bf(o[mt][0][reg] * si);
      attnout[ob + 16 + lr] = f2bf(o[mt][1][reg] * si);
    }
  }
}

// ---------------- launch ----------------
extern "C" void kernel_launch(void* const* d_in, const int* in_sizes, int n_in,
                              void* d_out, int out_size, void* d_ws, size_t ws_size,
                              hipStream_t stream) {
  const float* x       = (const float*)d_in[0];
  const float* qkv_w   = (const float*)d_in[1];
  const float* q_bias  = (const float*)d_in[2];
  const float* v_bias  = (const float*)d_in[3];
  const float* lscale  = (const float*)d_in[4];
  const float* cpb_w1  = (const float*)d_in[5];
  const float* cpb_b1  = (const float*)d_in[6];
  const float* cpb_w2  = (const float*)d_in[7];
  const float* proj_w  = (const float*)d_in[8];
  const float* proj_b  = (const float*)d_in[9];
  const float* norm1_w = (const float*)d_in[10];
  const float* norm2_w = (const float*)d_in[11];
  const float* mlp_w1  = (const float*)d_in[12];
  const float* mlp_b1  = (const float*)d_in[13];
  const float* mlp_w2  = (const float*)d_in[14];
  const float* mlp_b2  = (const float*)d_in[15];
  float* outp = (float*)d_out;
  char* ws = (char*)d_ws;

  unsigned short* w1b     = (unsigned short*)(ws + 0);          // persist
  unsigned short* w2b     = (unsigned short*)(ws + 2097152);    // persist
  unsigned short* qkv_wb  = (unsigned short*)(ws + 4194304);    // persist
  unsigned short* proj_wb = (unsigned short*)(ws + 5767168);    // persist
  float*          sig_tbl = (float*)(ws + 6291456);             // persist
  float*          qkvb    = (float*)(ws + 6311936);             // persist
  unsigned short* xb      = (unsigned short*)(ws + 8388608);    // [8,40)   prep->qkv
  unsigned short* attnout = (unsigned short*)(ws + 8388608);    // [8,40)   attn->proj
  unsigned short* x1b     = (unsigned short*)(ws + 8388608);    // [8,40)   addn1->mlp1
  unsigned short* qkvbuf  = (unsigned short*)(ws + 41943040);   // [40,136) qkv->attn
  unsigned short* projy   = (unsigned short*)(ws + 41943040);   // [40,72)  proj->addn1
  unsigned short* mlp2y   = (unsigned short*)(ws + 41943040);   // [40,72)  mlp2h->addn2h
  unsigned short* h2buf   = (unsigned short*)(ws + 75497472);   // [72,136) mlp1h->mlp2h

  cvt8_k<<<512, 256, 0, stream>>>(mlp_w1, w1b, 131072);
  cvt8_k<<<512, 256, 0, stream>>>(mlp_w2, w2b, 131072);
  cvt8_k<<<384, 256, 0, stream>>>(qkv_w, qkv_wb, 98304);
  cvt8_k<<<128, 256, 0, stream>>>(proj_w, proj_wb, 32768);
  rollcvt_k<<<8192, 256, 0, stream>>>(x, xb);
  cpb_k<<<255, 256, 0, stream>>>(cpb_w1, cpb_b1, cpb_w2, sig_tbl);
  qkvbias_k<<<6, 256, 0, stream>>>(q_bias, v_bias, qkvb);

  // qkv = xb @ qkv_w^T + qkvb
  qkv_gemm<<<3072, 256, 0, stream>>>(xb, qkv_wb, qkvb, qkvbuf);
  // attention
  attn_k<<<dim3(16, 256), 256, 0, stream>>>(qkvbuf, lscale, sig_tbl, attnout);
  // proj (plain bf16 out) + rolled addnorm (writes outp f32 + x1b bf16)
  proj_gemm<<<1024, 256, 0, stream>>>(attnout, proj_wb, proj_b, projy);
  addnorm_roll_k<<<32768, 128, 0, stream>>>(projy, x, norm1_w, outp, x1b);
  // MLP in two 16K-row halves sharing h2buf (64 MB)
  for (int half = 0; half < 2; ++half) {
    const long r0 = (long)half * 16384;
    mlp1_gemm<<<2048, 256, 0, stream>>>(x1b + r0 * 512, w1b, mlp_b1, h2buf);
    mlp2_gemm<<<512, 256, 0, stream>>>(h2buf, w2b, mlp_b2, mlp2y);
    addnorm_final_k<<<16384, 128, 0, stream>>>(mlp2y, norm2_w, outp, (int)r0);
  }
}

// Round 12
// 457.910 us; speedup vs baseline: 1.0386x; 1.0386x over previous
//
#include <hip/hip_runtime.h>

typedef __attribute__((ext_vector_type(8))) unsigned short us8;
typedef __attribute__((ext_vector_type(4))) unsigned short us4;
typedef __attribute__((ext_vector_type(8))) short bf16x8;
typedef __attribute__((ext_vector_type(4))) float f32x4;

#define LMASK 16383
#define SQRT_C 22.627416997969522f
#define LOGIT_MAXV 4.605170185988091f

__device__ __forceinline__ float bf2f(unsigned short u) {
  unsigned int x = ((unsigned int)u) << 16;
  return __builtin_bit_cast(float, x);
}
__device__ __forceinline__ unsigned short f2bf(float f) {
  unsigned int x = __builtin_bit_cast(unsigned int, f);
  x = x + 0x7FFFu + ((x >> 16) & 1u);
  return (unsigned short)(x >> 16);
}
__device__ __forceinline__ void gload16(const void* g, void* lds) {
  __builtin_amdgcn_global_load_lds(
      (const __attribute__((address_space(1))) unsigned int*)g,
      (__attribute__((address_space(3))) unsigned int*)lds, 16, 0, 0);
}

// ---------------- merged prep kernel ----------------
// blocks [0,1536): weight f32->bf16 converts; [1536,1542): qkv bias concat;
// [1542,9734): roll(x,-64) + convert to bf16.
__global__ void prep_k(const float* __restrict__ mlp_w1, const float* __restrict__ mlp_w2,
                       const float* __restrict__ qkv_w, const float* __restrict__ proj_w,
                       const float* __restrict__ qb, const float* __restrict__ vb,
                       const float* __restrict__ x,
                       unsigned short* __restrict__ w1b, unsigned short* __restrict__ w2b,
                       unsigned short* __restrict__ qkv_wb, unsigned short* __restrict__ proj_wb,
                       float* __restrict__ qkvb, unsigned short* __restrict__ xb) {
  const int b = blockIdx.x;
  const int tid = threadIdx.x;
  if (b < 1536) {
    const float* src;
    unsigned short* dst;
    int base;
    if (b < 512)       { src = mlp_w1; dst = w1b;    base = b; }
    else if (b < 1024) { src = mlp_w2; dst = w2b;    base = b - 512; }
    else if (b < 1408) { src = qkv_w;  dst = qkv_wb; base = b - 1024; }
    else               { src = proj_w; dst = proj_wb; base = b - 1408; }
    const long idx = (long)base * 256 + tid;
    const float* s = src + idx * 8;
    us8 u;
    #pragma unroll
    for (int e = 0; e < 8; ++e) u[e] = f2bf(s[e]);
    *(us8*)(dst + idx * 8) = u;
  } else if (b < 1542) {
    const int n = (b - 1536) * 256 + tid;
    float v = 0.f;
    if (n < 512) v = qb[n];
    else if (n >= 1024) v = vb[n - 1024];
    qkvb[n] = v;
  } else {
    long e = ((long)(b - 1542) * 256 + tid) * 8;
    long row = e >> 9;
    int col = (int)(e & 511);
    long src = ((row >> 14) << 14) | (((row & LMASK) + 64) & LMASK);
    const float* s = x + src * 512 + col;
    us8 u;
    #pragma unroll
    for (int ee = 0; ee < 8; ++ee) u[ee] = f2bf(s[ee]);
    *(us8*)(xb + e) = u;
  }
}

__global__ __launch_bounds__(256) void cpb_k(const float* __restrict__ w1,
    const float* __restrict__ b1, const float* __restrict__ w2,
    float* __restrict__ sig_tbl) {
  __shared__ float hbuf[512];
  const int i = blockIdx.x;
  const int tid = threadIdx.x;
  const float t = (float)(i - 127) * (8.f / 127.f);
  const float sgn = (t < 0.f) ? -1.f : 1.f;
  const float s = sgn * (log2f(fabsf(t) + 1.f) * (1.f / 3.f));
  hbuf[tid]       = fmaxf(s * w1[tid] + b1[tid], 0.f);
  hbuf[tid + 256] = fmaxf(s * w1[tid + 256] + b1[tid + 256], 0.f);
  __syncthreads();
  const int wv = tid >> 6, lane = tid & 63;
  for (int q = 0; q < 4; ++q) {
    const int n = wv * 4 + q;
    float part = 0.f;
    for (int c = lane; c < 512; c += 64) part += hbuf[c] * w2[n * 512 + c];
    #pragma unroll
    for (int o = 1; o < 64; o <<= 1) part += __shfl_xor(part, o);
    if (lane == 0) sig_tbl[i * 16 + n] = 16.f / (1.f + expf(-part));
  }
}

// ============ m97-replica GEMM: 128x128, BK=32, 4 waves, 16 KB LDS ============
// Simple 2-barrier structure, compiler-scheduled. XCD-chunked 1-D grid, n-fast.
template<int NY, int EPI>
__device__ __forceinline__ void gemmS_body(
    const unsigned short* __restrict__ Ab, const unsigned short* __restrict__ Bw,
    const float* __restrict__ bias, unsigned short* __restrict__ outb, int K) {
  __shared__ unsigned short As[128 * 32];
  __shared__ unsigned short Bs[128 * 32];
  const int N = NY * 128;
  const int tid = threadIdx.x;
  const int w = tid >> 6, l = tid & 63;
  const int wrow = w >> 1, wcol = w & 1;
  const int nwg = gridDim.x;
  const int id = blockIdx.x;
  const int lid = (id & 7) * (nwg >> 3) + (id >> 3);
  const int mi = lid / NY, ni = lid - mi * NY;
  const int m0 = mi * 128, n0 = ni * 128;
  const int lr = l & 15, lh = l >> 4;
  f32x4 acc[4][4];
  #pragma unroll
  for (int m = 0; m < 4; ++m)
    #pragma unroll
    for (int n = 0; n < 4; ++n) acc[m][n] = (f32x4)0.f;
  const int fsw = (lr >> 1) & 3;
  int aoff[4], boff[4];
  #pragma unroll
  for (int m = 0; m < 4; ++m)
    aoff[m] = (wrow * 64 + m * 16 + lr) * 64 + ((lh ^ fsw) << 4);
  #pragma unroll
  for (int n = 0; n < 4; ++n)
    boff[n] = (wcol * 64 + n * 16 + lr) * 64 + ((lh ^ fsw) << 4);
  const int srow = l >> 2;
  const int schunk = (l & 3) ^ ((srow >> 1) & 3);

  for (int k0 = 0; k0 < K; k0 += 32) {
    __syncthreads();
    gload16(Ab + (long)(m0 + w * 16 + srow) * K + k0 + schunk * 8, (char*)As + w * 1024);
    gload16(Ab + (long)(m0 + 64 + w * 16 + srow) * K + k0 + schunk * 8,
            (char*)As + 4096 + w * 1024);
    gload16(Bw + (long)(n0 + w * 16 + srow) * K + k0 + schunk * 8, (char*)Bs + w * 1024);
    gload16(Bw + (long)(n0 + 64 + w * 16 + srow) * K + k0 + schunk * 8,
            (char*)Bs + 4096 + w * 1024);
    __syncthreads();
    bf16x8 a[4], b[4];
    #pragma unroll
    for (int m = 0; m < 4; ++m) a[m] = *(const bf16x8*)((const char*)As + aoff[m]);
    #pragma unroll
    for (int n = 0; n < 4; ++n) b[n] = *(const bf16x8*)((const char*)Bs + boff[n]);
    #pragma unroll
    for (int m = 0; m < 4; ++m)
      #pragma unroll
      for (int n = 0; n < 4; ++n)
        acc[m][n] = __builtin_amdgcn_mfma_f32_16x16x32_bf16(a[m], b[n], acc[m][n], 0, 0, 0);
  }

  float bv[4];
  #pragma unroll
  for (int n = 0; n < 4; ++n) bv[n] = bias[n0 + wcol * 64 + n * 16 + lr];
  #pragma unroll
  for (int m = 0; m < 4; ++m)
    #pragma unroll
    for (int reg = 0; reg < 4; ++reg) {
      const long row = m0 + wrow * 64 + m * 16 + lh * 4 + reg;
      #pragma unroll
      for (int n = 0; n < 4; ++n) {
        const int col = n0 + wcol * 64 + n * 16 + lr;
        float v = acc[m][n][reg] + bv[n];
        if constexpr (EPI == 3) v = v / (1.f + __expf(-v));
        outb[row * (long)N + col] = f2bf(v);
      }
    }
}

__global__ __launch_bounds__(256) void qkv_gemm(
    const unsigned short* __restrict__ A, const unsigned short* __restrict__ B,
    const float* __restrict__ bias, unsigned short* __restrict__ C) {
  gemmS_body<12, 2>(A, B, bias, C, 512);
}
__global__ __launch_bounds__(256) void mlp1_gemm(
    const unsigned short* __restrict__ A, const unsigned short* __restrict__ B,
    const float* __restrict__ bias, unsigned short* __restrict__ C) {
  gemmS_body<16, 3>(A, B, bias, C, 512);
}
__global__ __launch_bounds__(256) void mlp2_gemm(
    const unsigned short* __restrict__ A, const unsigned short* __restrict__ B,
    const float* __restrict__ bias, unsigned short* __restrict__ C) {
  gemmS_body<4, 2>(A, B, bias, C, 2048);
}

// ============ projf: 128x512 full-row proj + fused RMS-norm1 + rolled residual ==
// Simple 2-barrier structure, 8 waves. Writes outp f32 AND x1b bf16 (mlp1 input).
__global__ __launch_bounds__(512) void projf_gemm(
    const unsigned short* __restrict__ Ab, const unsigned short* __restrict__ Bw,
    const float* __restrict__ bias, const float* __restrict__ resid,
    const float* __restrict__ nw, float* __restrict__ outf,
    unsigned short* __restrict__ x1b) {
  const int K = 512;
  __shared__ unsigned short As[128 * 32];
  __shared__ unsigned short Bs[512 * 32];
  __shared__ float rsum[128][4];
  __shared__ float rinv[128];
  const int tid = threadIdx.x;
  const int ww = tid >> 6, l = tid & 63;
  const int wrow = ww >> 2, wcol = ww & 3;
  const int nwg = gridDim.x;
  const int id = blockIdx.x;
  const int lid = (id & 7) * (nwg >> 3) + (id >> 3);
  const int m0 = lid * 128;
  const int lr = l & 15, lh = l >> 4;
  f32x4 acc[4][8];
  #pragma unroll
  for (int m = 0; m < 4; ++m)
    #pragma unroll
    for (int n = 0; n < 8; ++n) acc[m][n] = (f32x4)0.f;
  const int fsw = (lr >> 1) & 3;
  int aoff[4], boff[8];
  #pragma unroll
  for (int m = 0; m < 4; ++m)
    aoff[m] = (wrow * 64 + m * 16 + lr) * 64 + ((lh ^ fsw) << 4);
  #pragma unroll
  for (int n = 0; n < 8; ++n)
    boff[n] = (wcol * 128 + n * 16 + lr) * 64 + ((lh ^ fsw) << 4);
  const int srow = l >> 2;
  const int schunk = (l & 3) ^ ((srow >> 1) & 3);

  for (int k0 = 0; k0 < K; k0 += 32) {
    __syncthreads();
    gload16(Ab + (long)(m0 + ww * 16 + srow) * K + k0 + schunk * 8, (char*)As + ww * 1024);
    #pragma unroll
    for (int c = 0; c < 4; ++c)
      gload16(Bw + (long)(c * 128 + ww * 16 + srow) * K + k0 + schunk * 8,
              (char*)Bs + c * 8192 + ww * 1024);
    __syncthreads();
    bf16x8 a[4], b[8];
    #pragma unroll
    for (int m = 0; m < 4; ++m) a[m] = *(const bf16x8*)((const char*)As + aoff[m]);
    #pragma unroll
    for (int n = 0; n < 8; ++n) b[n] = *(const bf16x8*)((const char*)Bs + boff[n]);
    #pragma unroll
    for (int m = 0; m < 4; ++m)
      #pragma unroll
      for (int n = 0; n < 8; ++n)
        acc[m][n] = __builtin_amdgcn_mfma_f32_16x16x32_bf16(a[m], b[n], acc[m][n], 0, 0, 0);
  }

  // fused epilogue: bias -> row RMS -> rolled residual -> outp f32 + x1b bf16
  float bv[8], nwv[8];
  #pragma unroll
  for (int n = 0; n < 8; ++n) {
    const int col = wcol * 128 + n * 16 + lr;
    bv[n] = bias[col];
    nwv[n] = nw[col];
  }
  float part[4][4];
  #pragma unroll
  for (int m = 0; m < 4; ++m)
    #pragma unroll
    for (int reg = 0; reg < 4; ++reg) {
      float s = 0.f;
      #pragma unroll
      for (int n = 0; n < 8; ++n) {
        float v = acc[m][n][reg] + bv[n];
        s += v * v;
      }
      part[m][reg] = s;
    }
  #pragma unroll
  for (int off = 1; off < 16; off <<= 1)
    #pragma unroll
    for (int m = 0; m < 4; ++m)
      #pragma unroll
      for (int reg = 0; reg < 4; ++reg)
        part[m][reg] += __shfl_xor(part[m][reg], off);
  if (lr == 0) {
    #pragma unroll
    for (int m = 0; m < 4; ++m)
      #pragma unroll
      for (int reg = 0; reg < 4; ++reg)
        rsum[wrow * 64 + m * 16 + lh * 4 + reg][wcol] = part[m][reg];
  }
  __syncthreads();
  if (tid < 128) {
    float s = rsum[tid][0] + rsum[tid][1] + rsum[tid][2] + rsum[tid][3];
    rinv[tid] = SQRT_C * rsqrtf(s * (1.f / 512.f) + 1e-8f);
  }
  __syncthreads();
  #pragma unroll
  for (int m = 0; m < 4; ++m)
    #pragma unroll
    for (int reg = 0; reg < 4; ++reg) {
      const int rl = wrow * 64 + m * 16 + lh * 4 + reg;
      const long grow = m0 + rl;
      const float inv = rinv[rl];
      const long orow = (grow & ~(long)LMASK) | (((grow & LMASK) + 64) & LMASK);
      #pragma unroll
      for (int n = 0; n < 8; ++n) {
        const int col = wcol * 128 + n * 16 + lr;
        float v = acc[m][n][reg] + bv[n];
        float o = resid[orow * 512 + col] + v * inv * nwv[n];
        outf[orow * 512 + col] = o;
        x1b[orow * 512 + col] = f2bf(o);
      }
    }
}

// ---- addnorm2: out[r0+r] += rms(y[r])*nw (in place on d_out) ----
__global__ __launch_bounds__(128) void addnorm_final_k(const unsigned short* __restrict__ y,
    const float* __restrict__ nw, float* __restrict__ out, int r0) {
  const int r = blockIdx.x;
  const int tid = threadIdx.x;
  us4 u = *(const us4*)(y + (long)r * 512 + tid * 4);
  float v0 = bf2f(u[0]), v1 = bf2f(u[1]), v2 = bf2f(u[2]), v3 = bf2f(u[3]);
  float ss = v0 * v0 + v1 * v1 + v2 * v2 + v3 * v3;
  #pragma unroll
  for (int o = 1; o < 64; o <<= 1) ss += __shfl_xor(ss, o);
  __shared__ float tot[2];
  if ((tid & 63) == 0) tot[tid >> 6] = ss;
  __syncthreads();
  const float inv = SQRT_C * rsqrtf((tot[0] + tot[1]) * (1.f / 512.f) + 1e-8f);
  const long base = (long)(r0 + r) * 512 + tid * 4;
  float4 wv = *(const float4*)(nw + tid * 4);
  float4 xv = *(const float4*)(out + base);
  float4 o4;
  o4.x = xv.x + v0 * inv * wv.x;
  o4.y = xv.y + v1 * inv * wv.y;
  o4.z = xv.z + v2 * inv * wv.z;
  o4.w = xv.w + v3 * inv * wv.w;
  *(float4*)(out + base) = o4;
}

// ---------------- attention via MFMA: one block per (head, window) ----------------
__global__ __launch_bounds__(256, 2) void attn_k(const unsigned short* __restrict__ qkv,
    const float* __restrict__ logit_scale, const float* __restrict__ sig_tbl,
    unsigned short* __restrict__ attnout) {
  __shared__ unsigned short qs[128 * 32];
  __shared__ unsigned short ks[128 * 32];
  __shared__ unsigned short vt[32 * 136];
  __shared__ unsigned short ps[128 * 136];
  __shared__ float qinv[128], kinv[128], lbias[256];
  const int h = blockIdx.x, w = blockIdx.y;
  const int tid = threadIdx.x;
  const int wv = tid >> 6, l = tid & 63;
  const int lr = l & 15, quad = l >> 4;

  {
    const int srow = l >> 2;
    const int cs = (l & 3) ^ ((srow >> 1) & 3);
    #pragma unroll
    for (int rnd = 0; rnd < 2; ++rnd) {
      const int row = wv * 32 + rnd * 16 + srow;
      const long gb = (long)(w * 128 + row) * 1536 + h * 32 + cs * 8;
      gload16(qkv + gb, (char*)qs + (wv * 32 + rnd * 16) * 64);
      gload16(qkv + gb + 512, (char*)ks + (wv * 32 + rnd * 16) * 64);
    }
  }
  #pragma unroll
  for (int rnd = 0; rnd < 2; ++rnd) {
    const int j = wv * 32 + rnd * 16 + (l >> 2);
    const int d0 = (l & 3) * 8;
    us8 uv = *(const us8*)(qkv + (long)(w * 128 + j) * 1536 + h * 32 + 1024 + d0);
    #pragma unroll
    for (int e = 0; e < 8; ++e) vt[(d0 + e) * 136 + j] = uv[e];
  }
  if (tid < 255) lbias[tid] = sig_tbl[tid * 16 + h];
  __syncthreads();

  const float scale = __expf(fminf(logit_scale[h], LOGIT_MAXV));
  {
    const int r = tid >> 1, cp = tid & 1;
    const int sw = (r >> 1) & 3;
    float sq = 0.f, sk = 0.f;
    #pragma unroll
    for (int cc = 0; cc < 2; ++cc) {
      const int slot = (cp * 2 + cc) ^ sw;
      us8 uq = *(const us8*)(qs + r * 32 + slot * 8);
      us8 uk = *(const us8*)(ks + r * 32 + slot * 8);
      #pragma unroll
      for (int e = 0; e < 8; ++e) {
        float fq = bf2f(uq[e]), fk = bf2f(uk[e]);
        sq = fmaf(fq, fq, sq);
        sk = fmaf(fk, fk, sk);
      }
    }
    sq += __shfl_xor(sq, 1);
    sk += __shfl_xor(sk, 1);
    qinv[r] = scale / fmaxf(sqrtf(sq), 1e-12f);
    kinv[r] = 1.f / fmaxf(sqrtf(sk), 1e-12f);
  }
  __syncthreads();

  const int fsw = (lr >> 1) & 3;
  bf16x8 aq[2];
  #pragma unroll
  for (int mt = 0; mt < 2; ++mt)
    aq[mt] = *(const bf16x8*)((const char*)qs + (wv * 32 + mt * 16 + lr) * 64 + ((quad ^ fsw) << 4));
  f32x4 s[2][8];
  #pragma unroll
  for (int nt = 0; nt < 8; ++nt) {
    bf16x8 bk = *(const bf16x8*)((const char*)ks + (nt * 16 + lr) * 64 + ((quad ^ fsw) << 4));
    #pragma unroll
    for (int mt = 0; mt < 2; ++mt)
      s[mt][nt] = __builtin_amdgcn_mfma_f32_16x16x32_bf16(aq[mt], bk, (f32x4)0.f, 0, 0, 0);
  }

  float kv8[8];
  #pragma unroll
  for (int nt = 0; nt < 8; ++nt) kv8[nt] = kinv[nt * 16 + lr];
  const bool lastwin = ((w & 127) == 127);
  const bool ihalf = (wv < 2);
  float sum[2][4];
  #pragma unroll
  for (int mt = 0; mt < 2; ++mt) {
    #pragma unroll
    for (int reg = 0; reg < 4; ++reg) {
      const int row = wv * 32 + mt * 16 + quad * 4 + reg;
      const float qv = qinv[row];
      const int bb = row + 127 - lr;
      float m = -1e30f;
      #pragma unroll
      for (int nt = 0; nt < 8; ++nt) {
        float v = s[mt][nt][reg] * qv * kv8[nt] + lbias[bb - nt * 16];
        if (lastwin && (ihalf != (nt < 4))) v -= 100.f;
        s[mt][nt][reg] = v;
        m = fmaxf(m, v);
      }
      m = fmaxf(m, __shfl_xor(m, 1));
      m = fmaxf(m, __shfl_xor(m, 2));
      m = fmaxf(m, __shfl_xor(m, 4));
      m = fmaxf(m, __shfl_xor(m, 8));
      float sm = 0.f;
      #pragma unroll
      for (int nt = 0; nt < 8; ++nt) {
        float p = __expf(s[mt][nt][reg] - m);
        s[mt][nt][reg] = p;
        sm += p;
      }
      sm += __shfl_xor(sm, 1);
      sm += __shfl_xor(sm, 2);
      sm += __shfl_xor(sm, 4);
      sm += __shfl_xor(sm, 8);
      sum[mt][reg] = sm;
      #pragma unroll
      for (int nt = 0; nt < 8; ++nt)
        ps[row * 136 + nt * 16 + lr] = f2bf(s[mt][nt][reg]);
    }
  }
  __syncthreads();

  f32x4 o[2][2];
  #pragma unroll
  for (int mt = 0; mt < 2; ++mt)
    #pragma unroll
    for (int nt = 0; nt < 2; ++nt) o[mt][nt] = (f32x4)0.f;
  #pragma unroll
  for (int kt = 0; kt < 4; ++kt) {
    bf16x8 pa[2], vb[2];
    #pragma unroll
    for (int mt = 0; mt < 2; ++mt)
      pa[mt] = *(const bf16x8*)((const char*)ps + (wv * 32 + mt * 16 + lr) * 272 + (kt * 4 + quad) * 16);
    #pragma unroll
    for (int nt = 0; nt < 2; ++nt)
      vb[nt] = *(const bf16x8*)((const char*)vt + (nt * 16 + lr) * 272 + (kt * 4 + quad) * 16);
    #pragma unroll
    for (int mt = 0; mt < 2; ++mt)
      #pragma unroll
      for (int nt = 0; nt < 2; ++nt)
        o[mt][nt] = __builtin_amdgcn_mfma_f32_16x16x32_bf16(pa[mt], vb[nt], o[mt][nt], 0, 0, 0);
  }
  #pragma unroll
  for (int mt = 0; mt < 2; ++mt) {
    #pragma unroll
    for (int reg = 0; reg < 4; ++reg) {
      const int row = wv * 32 + mt * 16 + quad * 4 + reg;
      const float si = 1.f / sum[mt][reg];
      const long ob = (long)(w * 128 + row) * 512 + h * 32;
      attnout[ob + lr]      = f2bf(o[mt][0][reg] * si);
      attnout[ob + 16 + lr] = f2bf(o[mt][1][reg] * si);
    }
  }
}

// ---------------- launch ----------------
extern "C" void kernel_launch(void* const* d_in, const int* in_sizes, int n_in,
                              void* d_out, int out_size, void* d_ws, size_t ws_size,
                              hipStream_t stream) {
  const float* x       = (const float*)d_in[0];
  const float* qkv_w   = (const float*)d_in[1];
  const float* q_bias  = (const float*)d_in[2];
  const float* v_bias  = (const float*)d_in[3];
  const float* lscale  = (const float*)d_in[4];
  const float* cpb_w1  = (const float*)d_in[5];
  const float* cpb_b1  = (const float*)d_in[6];
  const float* cpb_w2  = (const float*)d_in[7];
  const float* proj_w  = (const float*)d_in[8];
  const float* proj_b  = (const float*)d_in[9];
  const float* norm1_w = (const float*)d_in[10];
  const float* norm2_w = (const float*)d_in[11];
  const float* mlp_w1  = (const float*)d_in[12];
  const float* mlp_b1  = (const float*)d_in[13];
  const float* mlp_w2  = (const float*)d_in[14];
  const float* mlp_b2  = (const float*)d_in[15];
  float* outp = (float*)d_out;
  char* ws = (char*)d_ws;

  unsigned short* w1b     = (unsigned short*)(ws + 0);          // persist
  unsigned short* w2b     = (unsigned short*)(ws + 2097152);    // persist
  unsigned short* qkv_wb  = (unsigned short*)(ws + 4194304);    // persist
  unsigned short* proj_wb = (unsigned short*)(ws + 5767168);    // persist
  float*          sig_tbl = (float*)(ws + 6291456);             // persist
  float*          qkvb    = (float*)(ws + 6311936);             // persist
  unsigned short* xb      = (unsigned short*)(ws + 8388608);    // [8,40)   prep->qkv
  unsigned short* attnout = (unsigned short*)(ws + 8388608);    // [8,40)   attn->proj
  unsigned short* x1b     = (unsigned short*)(ws + 8388608);    // [8,40)   projf->mlp1
  unsigned short* qkvbuf  = (unsigned short*)(ws + 41943040);   // [40,136) qkv->attn
  unsigned short* mlp2y   = (unsigned short*)(ws + 41943040);   // [40,72)  mlp2h->addn2h
  unsigned short* h2buf   = (unsigned short*)(ws + 75497472);   // [72,136) mlp1h->mlp2h

  // prep: all weight converts + bias concat + rolled x convert (one launch)
  prep_k<<<9734, 256, 0, stream>>>(mlp_w1, mlp_w2, qkv_w, proj_w, q_bias, v_bias, x,
                                   w1b, w2b, qkv_wb, proj_wb, qkvb, xb);
  cpb_k<<<255, 256, 0, stream>>>(cpb_w1, cpb_b1, cpb_w2, sig_tbl);

  // qkv = xb @ qkv_w^T + qkvb
  qkv_gemm<<<3072, 256, 0, stream>>>(xb, qkv_wb, qkvb, qkvbuf);
  // attention
  attn_k<<<dim3(16, 256), 256, 0, stream>>>(qkvbuf, lscale, sig_tbl, attnout);
  // proj + fused RMS-norm1 + rolled residual -> outp f32, x1b bf16
  projf_gemm<<<256, 512, 0, stream>>>(attnout, proj_wb, proj_b, x, norm1_w, outp, x1b);
  // MLP in two 16K-row halves sharing h2buf (64 MB)
  for (int half = 0; half < 2; ++half) {
    const long r0 = (long)half * 16384;
    mlp1_gemm<<<2048, 256, 0, stream>>>(x1b + r0 * 512, w1b, mlp_b1, h2buf);
    mlp2_gemm<<<512, 256, 0, stream>>>(h2buf, w2b, mlp_b2, mlp2y);
    addnorm_final_k<<<16384, 128, 0, stream>>>(mlp2y, norm2_w, outp, (int)r0);
  }
}

// Round 13
// 455.807 us; speedup vs baseline: 1.0434x; 1.0046x over previous
//
#include <hip/hip_runtime.h>

typedef __attribute__((ext_vector_type(8))) unsigned short us8;
typedef __attribute__((ext_vector_type(4))) unsigned short us4;
typedef __attribute__((ext_vector_type(8))) short bf16x8;
typedef __attribute__((ext_vector_type(4))) float f32x4;

#define LMASK 16383
#define SQRT_C 22.627416997969522f
#define LOGIT_MAXV 4.605170185988091f

__device__ __forceinline__ float bf2f(unsigned short u) {
  unsigned int x = ((unsigned int)u) << 16;
  return __builtin_bit_cast(float, x);
}
__device__ __forceinline__ unsigned short f2bf(float f) {
  unsigned int x = __builtin_bit_cast(unsigned int, f);
  x = x + 0x7FFFu + ((x >> 16) & 1u);
  return (unsigned short)(x >> 16);
}
__device__ __forceinline__ void gload16(const void* g, void* lds) {
  __builtin_amdgcn_global_load_lds(
      (const __attribute__((address_space(1))) unsigned int*)g,
      (__attribute__((address_space(3))) unsigned int*)lds, 16, 0, 0);
}

// ---------------- merged prep kernel ----------------
__global__ void prep_k(const float* __restrict__ mlp_w1, const float* __restrict__ mlp_w2,
                       const float* __restrict__ qkv_w, const float* __restrict__ proj_w,
                       const float* __restrict__ qb, const float* __restrict__ vb,
                       const float* __restrict__ x,
                       unsigned short* __restrict__ w1b, unsigned short* __restrict__ w2b,
                       unsigned short* __restrict__ qkv_wb, unsigned short* __restrict__ proj_wb,
                       float* __restrict__ qkvb, unsigned short* __restrict__ xb) {
  const int b = blockIdx.x;
  const int tid = threadIdx.x;
  if (b < 1536) {
    const float* src;
    unsigned short* dst;
    int base;
    if (b < 512)       { src = mlp_w1; dst = w1b;    base = b; }
    else if (b < 1024) { src = mlp_w2; dst = w2b;    base = b - 512; }
    else if (b < 1408) { src = qkv_w;  dst = qkv_wb; base = b - 1024; }
    else               { src = proj_w; dst = proj_wb; base = b - 1408; }
    const long idx = (long)base * 256 + tid;
    const float* s = src + idx * 8;
    us8 u;
    #pragma unroll
    for (int e = 0; e < 8; ++e) u[e] = f2bf(s[e]);
    *(us8*)(dst + idx * 8) = u;
  } else if (b < 1542) {
    const int n = (b - 1536) * 256 + tid;
    float v = 0.f;
    if (n < 512) v = qb[n];
    else if (n >= 1024) v = vb[n - 1024];
    qkvb[n] = v;
  } else {
    long e = ((long)(b - 1542) * 256 + tid) * 8;
    long row = e >> 9;
    int col = (int)(e & 511);
    long src = ((row >> 14) << 14) | (((row & LMASK) + 64) & LMASK);
    const float* s = x + src * 512 + col;
    us8 u;
    #pragma unroll
    for (int ee = 0; ee < 8; ++ee) u[ee] = f2bf(s[ee]);
    *(us8*)(xb + e) = u;
  }
}

__global__ __launch_bounds__(256) void cpb_k(const float* __restrict__ w1,
    const float* __restrict__ b1, const float* __restrict__ w2,
    float* __restrict__ sig_tbl) {
  __shared__ float hbuf[512];
  const int i = blockIdx.x;
  const int tid = threadIdx.x;
  const float t = (float)(i - 127) * (8.f / 127.f);
  const float sgn = (t < 0.f) ? -1.f : 1.f;
  const float s = sgn * (log2f(fabsf(t) + 1.f) * (1.f / 3.f));
  hbuf[tid]       = fmaxf(s * w1[tid] + b1[tid], 0.f);
  hbuf[tid + 256] = fmaxf(s * w1[tid + 256] + b1[tid + 256], 0.f);
  __syncthreads();
  const int wv = tid >> 6, lane = tid & 63;
  for (int q = 0; q < 4; ++q) {
    const int n = wv * 4 + q;
    float part = 0.f;
    for (int c = lane; c < 512; c += 64) part += hbuf[c] * w2[n * 512 + c];
    #pragma unroll
    for (int o = 1; o < 64; o <<= 1) part += __shfl_xor(part, o);
    if (lane == 0) sig_tbl[i * 16 + n] = 16.f / (1.f + expf(-part));
  }
}

// ============ gemmS: 128x128 tile, BK=64, 4 waves, 32 KB LDS ============
// Simple 2-barrier structure, compiler-scheduled; half the barrier pairs of
// BK=32. Rows of 8x16B chunks; physical chunk = global ^ (row&7) (2-way banks
// = free). gload_lds dest linear; source chunk pre-swizzled (l&7)^(l>>3).
// ks=1 fragment address = ks=0 address ^ 0x40 (constant XOR).
template<int NY, int EPI>
__device__ __forceinline__ void gemmS_body(
    const unsigned short* __restrict__ Ab, const unsigned short* __restrict__ Bw,
    const float* __restrict__ bias, unsigned short* __restrict__ outb, int K) {
  __shared__ unsigned short As[128 * 64];
  __shared__ unsigned short Bs[128 * 64];
  const int N = NY * 128;
  const int tid = threadIdx.x;
  const int w = tid >> 6, l = tid & 63;
  const int wrow = w >> 1, wcol = w & 1;
  const int nwg = gridDim.x;
  const int id = blockIdx.x;
  const int lid = (id & 7) * (nwg >> 3) + (id >> 3);
  const int mi = lid / NY, ni = lid - mi * NY;
  const int m0 = mi * 128, n0 = ni * 128;
  const int lr = l & 15, lh = l >> 4;
  f32x4 acc[4][4];
  #pragma unroll
  for (int m = 0; m < 4; ++m)
    #pragma unroll
    for (int n = 0; n < 4; ++n) acc[m][n] = (f32x4)0.f;
  const int rl7 = lr & 7;
  int aoff[4], boff[4];
  #pragma unroll
  for (int m = 0; m < 4; ++m)
    aoff[m] = (wrow * 64 + m * 16 + lr) * 128 + ((lh ^ rl7) << 4);
  #pragma unroll
  for (int n = 0; n < 4; ++n)
    boff[n] = (wcol * 64 + n * 16 + lr) * 128 + ((lh ^ rl7) << 4);
  const int srow8 = l >> 3;                 // 0..7
  const int gch = (l & 7) ^ srow8;          // pre-swizzled source chunk

  for (int k0 = 0; k0 < K; k0 += 64) {
    __syncthreads();
    #pragma unroll
    for (int c = 0; c < 4; ++c) {
      const int slot = c * 4 + w;           // 0..15
      const int R = slot * 8 + srow8;       // row 0..127
      gload16(Ab + (long)(m0 + R) * K + k0 + gch * 8, (char*)As + slot * 1024);
      gload16(Bw + (long)(n0 + R) * K + k0 + gch * 8, (char*)Bs + slot * 1024);
    }
    __syncthreads();
    {
      bf16x8 a[4], b[4];
      #pragma unroll
      for (int m = 0; m < 4; ++m) a[m] = *(const bf16x8*)((const char*)As + aoff[m]);
      #pragma unroll
      for (int n = 0; n < 4; ++n) b[n] = *(const bf16x8*)((const char*)Bs + boff[n]);
      #pragma unroll
      for (int m = 0; m < 4; ++m)
        #pragma unroll
        for (int n = 0; n < 4; ++n)
          acc[m][n] = __builtin_amdgcn_mfma_f32_16x16x32_bf16(a[m], b[n], acc[m][n], 0, 0, 0);
    }
    {
      bf16x8 a[4], b[4];
      #pragma unroll
      for (int m = 0; m < 4; ++m) a[m] = *(const bf16x8*)((const char*)As + (aoff[m] ^ 64));
      #pragma unroll
      for (int n = 0; n < 4; ++n) b[n] = *(const bf16x8*)((const char*)Bs + (boff[n] ^ 64));
      #pragma unroll
      for (int m = 0; m < 4; ++m)
        #pragma unroll
        for (int n = 0; n < 4; ++n)
          acc[m][n] = __builtin_amdgcn_mfma_f32_16x16x32_bf16(a[m], b[n], acc[m][n], 0, 0, 0);
    }
  }

  float bv[4];
  #pragma unroll
  for (int n = 0; n < 4; ++n) bv[n] = bias[n0 + wcol * 64 + n * 16 + lr];
  #pragma unroll
  for (int m = 0; m < 4; ++m)
    #pragma unroll
    for (int reg = 0; reg < 4; ++reg) {
      const long row = m0 + wrow * 64 + m * 16 + lh * 4 + reg;
      #pragma unroll
      for (int n = 0; n < 4; ++n) {
        const int col = n0 + wcol * 64 + n * 16 + lr;
        float v = acc[m][n][reg] + bv[n];
        if constexpr (EPI == 3) v = v / (1.f + __expf(-v));
        outb[row * (long)N + col] = f2bf(v);
      }
    }
}

__global__ __launch_bounds__(256) void qkv_gemm(
    const unsigned short* __restrict__ A, const unsigned short* __restrict__ B,
    const float* __restrict__ bias, unsigned short* __restrict__ C) {
  gemmS_body<12, 2>(A, B, bias, C, 512);
}
__global__ __launch_bounds__(256) void mlp1_gemm(
    const unsigned short* __restrict__ A, const unsigned short* __restrict__ B,
    const float* __restrict__ bias, unsigned short* __restrict__ C) {
  gemmS_body<16, 3>(A, B, bias, C, 512);
}
__global__ __launch_bounds__(256) void mlp2_gemm(
    const unsigned short* __restrict__ A, const unsigned short* __restrict__ B,
    const float* __restrict__ bias, unsigned short* __restrict__ C) {
  gemmS_body<4, 2>(A, B, bias, C, 2048);
}

// ============ projf: 128x512 proj + fused RMS-norm1 + rolled residual ========
__global__ __launch_bounds__(512) void projf_gemm(
    const unsigned short* __restrict__ Ab, const unsigned short* __restrict__ Bw,
    const float* __restrict__ bias, const float* __restrict__ resid,
    const float* __restrict__ nw, float* __restrict__ outf,
    unsigned short* __restrict__ x1b) {
  const int K = 512;
  __shared__ unsigned short As[128 * 32];
  __shared__ unsigned short Bs[512 * 32];
  __shared__ float rsum[128][4];
  __shared__ float rinv[128];
  const int tid = threadIdx.x;
  const int ww = tid >> 6, l = tid & 63;
  const int wrow = ww >> 2, wcol = ww & 3;
  const int nwg = gridDim.x;
  const int id = blockIdx.x;
  const int lid = (id & 7) * (nwg >> 3) + (id >> 3);
  const int m0 = lid * 128;
  const int lr = l & 15, lh = l >> 4;
  f32x4 acc[4][8];
  #pragma unroll
  for (int m = 0; m < 4; ++m)
    #pragma unroll
    for (int n = 0; n < 8; ++n) acc[m][n] = (f32x4)0.f;
  const int fsw = (lr >> 1) & 3;
  int aoff[4], boff[8];
  #pragma unroll
  for (int m = 0; m < 4; ++m)
    aoff[m] = (wrow * 64 + m * 16 + lr) * 64 + ((lh ^ fsw) << 4);
  #pragma unroll
  for (int n = 0; n < 8; ++n)
    boff[n] = (wcol * 128 + n * 16 + lr) * 64 + ((lh ^ fsw) << 4);
  const int srow = l >> 2;
  const int schunk = (l & 3) ^ ((srow >> 1) & 3);

  for (int k0 = 0; k0 < K; k0 += 32) {
    __syncthreads();
    gload16(Ab + (long)(m0 + ww * 16 + srow) * K + k0 + schunk * 8, (char*)As + ww * 1024);
    #pragma unroll
    for (int c = 0; c < 4; ++c)
      gload16(Bw + (long)(c * 128 + ww * 16 + srow) * K + k0 + schunk * 8,
              (char*)Bs + c * 8192 + ww * 1024);
    __syncthreads();
    bf16x8 a[4], b[8];
    #pragma unroll
    for (int m = 0; m < 4; ++m) a[m] = *(const bf16x8*)((const char*)As + aoff[m]);
    #pragma unroll
    for (int n = 0; n < 8; ++n) b[n] = *(const bf16x8*)((const char*)Bs + boff[n]);
    #pragma unroll
    for (int m = 0; m < 4; ++m)
      #pragma unroll
      for (int n = 0; n < 8; ++n)
        acc[m][n] = __builtin_amdgcn_mfma_f32_16x16x32_bf16(a[m], b[n], acc[m][n], 0, 0, 0);
  }

  float bv[8], nwv[8];
  #pragma unroll
  for (int n = 0; n < 8; ++n) {
    const int col = wcol * 128 + n * 16 + lr;
    bv[n] = bias[col];
    nwv[n] = nw[col];
  }
  float part[4][4];
  #pragma unroll
  for (int m = 0; m < 4; ++m)
    #pragma unroll
    for (int reg = 0; reg < 4; ++reg) {
      float s = 0.f;
      #pragma unroll
      for (int n = 0; n < 8; ++n) {
        float v = acc[m][n][reg] + bv[n];
        s += v * v;
      }
      part[m][reg] = s;
    }
  #pragma unroll
  for (int off = 1; off < 16; off <<= 1)
    #pragma unroll
    for (int m = 0; m < 4; ++m)
      #pragma unroll
      for (int reg = 0; reg < 4; ++reg)
        part[m][reg] += __shfl_xor(part[m][reg], off);
  if (lr == 0) {
    #pragma unroll
    for (int m = 0; m < 4; ++m)
      #pragma unroll
      for (int reg = 0; reg < 4; ++reg)
        rsum[wrow * 64 + m * 16 + lh * 4 + reg][wcol] = part[m][reg];
  }
  __syncthreads();
  if (tid < 128) {
    float s = rsum[tid][0] + rsum[tid][1] + rsum[tid][2] + rsum[tid][3];
    rinv[tid] = SQRT_C * rsqrtf(s * (1.f / 512.f) + 1e-8f);
  }
  __syncthreads();
  #pragma unroll
  for (int m = 0; m < 4; ++m)
    #pragma unroll
    for (int reg = 0; reg < 4; ++reg) {
      const int rl = wrow * 64 + m * 16 + lh * 4 + reg;
      const long grow = m0 + rl;
      const float inv = rinv[rl];
      const long orow = (grow & ~(long)LMASK) | (((grow & LMASK) + 64) & LMASK);
      #pragma unroll
      for (int n = 0; n < 8; ++n) {
        const int col = wcol * 128 + n * 16 + lr;
        float v = acc[m][n][reg] + bv[n];
        float o = resid[orow * 512 + col] + v * inv * nwv[n];
        outf[orow * 512 + col] = o;
        x1b[orow * 512 + col] = f2bf(o);
      }
    }
}

// ---- addnorm2: out[r0+r] += rms(y[r])*nw (in place on d_out) ----
__global__ __launch_bounds__(128) void addnorm_final_k(const unsigned short* __restrict__ y,
    const float* __restrict__ nw, float* __restrict__ out, int r0) {
  const int r = blockIdx.x;
  const int tid = threadIdx.x;
  us4 u = *(const us4*)(y + (long)r * 512 + tid * 4);
  float v0 = bf2f(u[0]), v1 = bf2f(u[1]), v2 = bf2f(u[2]), v3 = bf2f(u[3]);
  float ss = v0 * v0 + v1 * v1 + v2 * v2 + v3 * v3;
  #pragma unroll
  for (int o = 1; o < 64; o <<= 1) ss += __shfl_xor(ss, o);
  __shared__ float tot[2];
  if ((tid & 63) == 0) tot[tid >> 6] = ss;
  __syncthreads();
  const float inv = SQRT_C * rsqrtf((tot[0] + tot[1]) * (1.f / 512.f) + 1e-8f);
  const long base = (long)(r0 + r) * 512 + tid * 4;
  float4 wv = *(const float4*)(nw + tid * 4);
  float4 xv = *(const float4*)(out + base);
  float4 o4;
  o4.x = xv.x + v0 * inv * wv.x;
  o4.y = xv.y + v1 * inv * wv.y;
  o4.z = xv.z + v2 * inv * wv.z;
  o4.w = xv.w + v3 * inv * wv.w;
  *(float4*)(out + base) = o4;
}

// ---------------- attention via MFMA: one block per (head, window) ----------------
__global__ __launch_bounds__(256, 2) void attn_k(const unsigned short* __restrict__ qkv,
    const float* __restrict__ logit_scale, const float* __restrict__ sig_tbl,
    unsigned short* __restrict__ attnout) {
  __shared__ unsigned short qs[128 * 32];
  __shared__ unsigned short ks[128 * 32];
  __shared__ unsigned short vt[32 * 136];
  __shared__ unsigned short ps[128 * 136];
  __shared__ float qinv[128], kinv[128], lbias[256];
  const int h = blockIdx.x, w = blockIdx.y;
  const int tid = threadIdx.x;
  const int wv = tid >> 6, l = tid & 63;
  const int lr = l & 15, quad = l >> 4;

  {
    const int srow = l >> 2;
    const int cs = (l & 3) ^ ((srow >> 1) & 3);
    #pragma unroll
    for (int rnd = 0; rnd < 2; ++rnd) {
      const int row = wv * 32 + rnd * 16 + srow;
      const long gb = (long)(w * 128 + row) * 1536 + h * 32 + cs * 8;
      gload16(qkv + gb, (char*)qs + (wv * 32 + rnd * 16) * 64);
      gload16(qkv + gb + 512, (char*)ks + (wv * 32 + rnd * 16) * 64);
    }
  }
  #pragma unroll
  for (int rnd = 0; rnd < 2; ++rnd) {
    const int j = wv * 32 + rnd * 16 + (l >> 2);
    const int d0 = (l & 3) * 8;
    us8 uv = *(const us8*)(qkv + (long)(w * 128 + j) * 1536 + h * 32 + 1024 + d0);
    #pragma unroll
    for (int e = 0; e < 8; ++e) vt[(d0 + e) * 136 + j] = uv[e];
  }
  if (tid < 255) lbias[tid] = sig_tbl[tid * 16 + h];
  __syncthreads();

  const float scale = __expf(fminf(logit_scale[h], LOGIT_MAXV));
  {
    const int r = tid >> 1, cp = tid & 1;
    const int sw = (r >> 1) & 3;
    float sq = 0.f, sk = 0.f;
    #pragma unroll
    for (int cc = 0; cc < 2; ++cc) {
      const int slot = (cp * 2 + cc) ^ sw;
      us8 uq = *(const us8*)(qs + r * 32 + slot * 8);
      us8 uk = *(const us8*)(ks + r * 32 + slot * 8);
      #pragma unroll
      for (int e = 0; e < 8; ++e) {
        float fq = bf2f(uq[e]), fk = bf2f(uk[e]);
        sq = fmaf(fq, fq, sq);
        sk = fmaf(fk, fk, sk);
      }
    }
    sq += __shfl_xor(sq, 1);
    sk += __shfl_xor(sk, 1);
    qinv[r] = scale / fmaxf(sqrtf(sq), 1e-12f);
    kinv[r] = 1.f / fmaxf(sqrtf(sk), 1e-12f);
  }
  __syncthreads();

  const int fsw = (lr >> 1) & 3;
  bf16x8 aq[2];
  #pragma unroll
  for (int mt = 0; mt < 2; ++mt)
    aq[mt] = *(const bf16x8*)((const char*)qs + (wv * 32 + mt * 16 + lr) * 64 + ((quad ^ fsw) << 4));
  f32x4 s[2][8];
  #pragma unroll
  for (int nt = 0; nt < 8; ++nt) {
    bf16x8 bk = *(const bf16x8*)((const char*)ks + (nt * 16 + lr) * 64 + ((quad ^ fsw) << 4));
    #pragma unroll
    for (int mt = 0; mt < 2; ++mt)
      s[mt][nt] = __builtin_amdgcn_mfma_f32_16x16x32_bf16(aq[mt], bk, (f32x4)0.f, 0, 0, 0);
  }

  float kv8[8];
  #pragma unroll
  for (int nt = 0; nt < 8; ++nt) kv8[nt] = kinv[nt * 16 + lr];
  const bool lastwin = ((w & 127) == 127);
  const bool ihalf = (wv < 2);
  float sum[2][4];
  #pragma unroll
  for (int mt = 0; mt < 2; ++mt) {
    #pragma unroll
    for (int reg = 0; reg < 4; ++reg) {
      const int row = wv * 32 + mt * 16 + quad * 4 + reg;
      const float qv = qinv[row];
      const int bb = row + 127 - lr;
      float m = -1e30f;
      #pragma unroll
      for (int nt = 0; nt < 8; ++nt) {
        float v = s[mt][nt][reg] * qv * kv8[nt] + lbias[bb - nt * 16];
        if (lastwin && (ihalf != (nt < 4))) v -= 100.f;
        s[mt][nt][reg] = v;
        m = fmaxf(m, v);
      }
      m = fmaxf(m, __shfl_xor(m, 1));
      m = fmaxf(m, __shfl_xor(m, 2));
      m = fmaxf(m, __shfl_xor(m, 4));
      m = fmaxf(m, __shfl_xor(m, 8));
      float sm = 0.f;
      #pragma unroll
      for (int nt = 0; nt < 8; ++nt) {
        float p = __expf(s[mt][nt][reg] - m);
        s[mt][nt][reg] = p;
        sm += p;
      }
      sm += __shfl_xor(sm, 1);
      sm += __shfl_xor(sm, 2);
      sm += __shfl_xor(sm, 4);
      sm += __shfl_xor(sm, 8);
      sum[mt][reg] = sm;
      #pragma unroll
      for (int nt = 0; nt < 8; ++nt)
        ps[row * 136 + nt * 16 + lr] = f2bf(s[mt][nt][reg]);
    }
  }
  __syncthreads();

  f32x4 o[2][2];
  #pragma unroll
  for (int mt = 0; mt < 2; ++mt)
    #pragma unroll
    for (int nt = 0; nt < 2; ++nt) o[mt][nt] = (f32x4)0.f;
  #pragma unroll
  for (int kt = 0; kt < 4; ++kt) {
    bf16x8 pa[2], vb[2];
    #pragma unroll
    for (int mt = 0; mt < 2; ++mt)
      pa[mt] = *(const bf16x8*)((const char*)ps + (wv * 32 + mt * 16 + lr) * 272 + (kt * 4 + quad) * 16);
    #pragma unroll
    for (int nt = 0; nt < 2; ++nt)
      vb[nt] = *(const bf16x8*)((const char*)vt + (nt * 16 + lr) * 272 + (kt * 4 + quad) * 16);
    #pragma unroll
    for (int mt = 0; mt < 2; ++mt)
      #pragma unroll
      for (int nt = 0; nt < 2; ++nt)
        o[mt][nt] = __builtin_amdgcn_mfma_f32_16x16x32_bf16(pa[mt], vb[nt], o[mt][nt], 0, 0, 0);
  }
  #pragma unroll
  for (int mt = 0; mt < 2; ++mt) {
    #pragma unroll
    for (int reg = 0; reg < 4; ++reg) {
      const int row = wv * 32 + mt * 16 + quad * 4 + reg;
      const float si = 1.f / sum[mt][reg];
      const long ob = (long)(w * 128 + row) * 512 + h * 32;
      attnout[ob + lr]      = f2bf(o[mt][0][reg] * si);
      attnout[ob + 16 + lr] = f2bf(o[mt][1][reg] * si);
    }
  }
}

// ---------------- launch ----------------
extern "C" void kernel_launch(void* const* d_in, const int* in_sizes, int n_in,
                              void* d_out, int out_size, void* d_ws, size_t ws_size,
                              hipStream_t stream) {
  const float* x       = (const float*)d_in[0];
  const float* qkv_w   = (const float*)d_in[1];
  const float* q_bias  = (const float*)d_in[2];
  const float* v_bias  = (const float*)d_in[3];
  const float* lscale  = (const float*)d_in[4];
  const float* cpb_w1  = (const float*)d_in[5];
  const float* cpb_b1  = (const float*)d_in[6];
  const float* cpb_w2  = (const float*)d_in[7];
  const float* proj_w  = (const float*)d_in[8];
  const float* proj_b  = (const float*)d_in[9];
  const float* norm1_w = (const float*)d_in[10];
  const float* norm2_w = (const float*)d_in[11];
  const float* mlp_w1  = (const float*)d_in[12];
  const float* mlp_b1  = (const float*)d_in[13];
  const float* mlp_w2  = (const float*)d_in[14];
  const float* mlp_b2  = (const float*)d_in[15];
  float* outp = (float*)d_out;
  char* ws = (char*)d_ws;

  unsigned short* w1b     = (unsigned short*)(ws + 0);          // persist
  unsigned short* w2b     = (unsigned short*)(ws + 2097152);    // persist
  unsigned short* qkv_wb  = (unsigned short*)(ws + 4194304);    // persist
  unsigned short* proj_wb = (unsigned short*)(ws + 5767168);    // persist
  float*          sig_tbl = (float*)(ws + 6291456);             // persist
  float*          qkvb    = (float*)(ws + 6311936);             // persist
  unsigned short* xb      = (unsigned short*)(ws + 8388608);    // [8,40)   prep->qkv
  unsigned short* attnout = (unsigned short*)(ws + 8388608);    // [8,40)   attn->projf
  unsigned short* x1b     = (unsigned short*)(ws + 8388608);    // [8,40)   projf->mlp1
  unsigned short* qkvbuf  = (unsigned short*)(ws + 41943040);   // [40,136) qkv->attn
  unsigned short* mlp2y   = (unsigned short*)(ws + 41943040);   // [40,72)  mlp2h->addn2h
  unsigned short* h2buf   = (unsigned short*)(ws + 75497472);   // [72,136) mlp1h->mlp2h

  prep_k<<<9734, 256, 0, stream>>>(mlp_w1, mlp_w2, qkv_w, proj_w, q_bias, v_bias, x,
                                   w1b, w2b, qkv_wb, proj_wb, qkvb, xb);
  cpb_k<<<255, 256, 0, stream>>>(cpb_w1, cpb_b1, cpb_w2, sig_tbl);

  // qkv = xb @ qkv_w^T + qkvb
  qkv_gemm<<<3072, 256, 0, stream>>>(xb, qkv_wb, qkvb, qkvbuf);
  // attention
  attn_k<<<dim3(16, 256), 256, 0, stream>>>(qkvbuf, lscale, sig_tbl, attnout);
  // proj + fused RMS-norm1 + rolled residual -> outp f32, x1b bf16
  projf_gemm<<<256, 512, 0, stream>>>(attnout, proj_wb, proj_b, x, norm1_w, outp, x1b);
  // MLP in two 16K-row halves sharing h2buf (64 MB)
  for (int half = 0; half < 2; ++half) {
    const long r0 = (long)half * 16384;
    mlp1_gemm<<<2048, 256, 0, stream>>>(x1b + r0 * 512, w1b, mlp_b1, h2buf);
    mlp2_gemm<<<512, 256, 0, stream>>>(h2buf, w2b, mlp_b2, mlp2y);
    addnorm_final_k<<<16384, 128, 0, stream>>>(mlp2y, norm2_w, outp, (int)r0);
  }
}

// Round 14
// 443.134 us; speedup vs baseline: 1.0733x; 1.0286x over previous
//
#include <hip/hip_runtime.h>

typedef __attribute__((ext_vector_type(8))) unsigned short us8;
typedef __attribute__((ext_vector_type(4))) unsigned short us4;
typedef __attribute__((ext_vector_type(8))) short bf16x8;
typedef __attribute__((ext_vector_type(4))) float f32x4;

#define LMASK 16383
#define SQRT_C 22.627416997969522f
#define LOGIT_MAXV 4.605170185988091f

__device__ __forceinline__ float bf2f(unsigned short u) {
  unsigned int x = ((unsigned int)u) << 16;
  return __builtin_bit_cast(float, x);
}
__device__ __forceinline__ unsigned short f2bf(float f) {
  unsigned int x = __builtin_bit_cast(unsigned int, f);
  x = x + 0x7FFFu + ((x >> 16) & 1u);
  return (unsigned short)(x >> 16);
}
__device__ __forceinline__ void gload16(const void* g, void* lds) {
  __builtin_amdgcn_global_load_lds(
      (const __attribute__((address_space(1))) unsigned int*)g,
      (__attribute__((address_space(3))) unsigned int*)lds, 16, 0, 0);
}

// ---------------- merged prep kernel ----------------
__global__ void prep_k(const float* __restrict__ mlp_w1, const float* __restrict__ mlp_w2,
                       const float* __restrict__ qkv_w, const float* __restrict__ proj_w,
                       const float* __restrict__ qb, const float* __restrict__ vb,
                       const float* __restrict__ x,
                       unsigned short* __restrict__ w1b, unsigned short* __restrict__ w2b,
                       unsigned short* __restrict__ qkv_wb, unsigned short* __restrict__ proj_wb,
                       float* __restrict__ qkvb, unsigned short* __restrict__ xb) {
  const int b = blockIdx.x;
  const int tid = threadIdx.x;
  if (b < 1536) {
    const float* src;
    unsigned short* dst;
    int base;
    if (b < 512)       { src = mlp_w1; dst = w1b;    base = b; }
    else if (b < 1024) { src = mlp_w2; dst = w2b;    base = b - 512; }
    else if (b < 1408) { src = qkv_w;  dst = qkv_wb; base = b - 1024; }
    else               { src = proj_w; dst = proj_wb; base = b - 1408; }
    const long idx = (long)base * 256 + tid;
    const float* s = src + idx * 8;
    us8 u;
    #pragma unroll
    for (int e = 0; e < 8; ++e) u[e] = f2bf(s[e]);
    *(us8*)(dst + idx * 8) = u;
  } else if (b < 1542) {
    const int n = (b - 1536) * 256 + tid;
    float v = 0.f;
    if (n < 512) v = qb[n];
    else if (n >= 1024) v = vb[n - 1024];
    qkvb[n] = v;
  } else {
    long e = ((long)(b - 1542) * 256 + tid) * 8;
    long row = e >> 9;
    int col = (int)(e & 511);
    long src = ((row >> 14) << 14) | (((row & LMASK) + 64) & LMASK);
    const float* s = x + src * 512 + col;
    us8 u;
    #pragma unroll
    for (int ee = 0; ee < 8; ++ee) u[ee] = f2bf(s[ee]);
    *(us8*)(xb + e) = u;
  }
}

__global__ __launch_bounds__(256) void cpb_k(const float* __restrict__ w1,
    const float* __restrict__ b1, const float* __restrict__ w2,
    float* __restrict__ sig_tbl) {
  __shared__ float hbuf[512];
  const int i = blockIdx.x;
  const int tid = threadIdx.x;
  const float t = (float)(i - 127) * (8.f / 127.f);
  const float sgn = (t < 0.f) ? -1.f : 1.f;
  const float s = sgn * (log2f(fabsf(t) + 1.f) * (1.f / 3.f));
  hbuf[tid]       = fmaxf(s * w1[tid] + b1[tid], 0.f);
  hbuf[tid + 256] = fmaxf(s * w1[tid + 256] + b1[tid + 256], 0.f);
  __syncthreads();
  const int wv = tid >> 6, lane = tid & 63;
  for (int q = 0; q < 4; ++q) {
    const int n = wv * 4 + q;
    float part = 0.f;
    for (int c = lane; c < 512; c += 64) part += hbuf[c] * w2[n * 512 + c];
    #pragma unroll
    for (int o = 1; o < 64; o <<= 1) part += __shfl_xor(part, o);
    if (lane == 0) sig_tbl[i * 16 + n] = 16.f / (1.f + expf(-part));
  }
}

// ============ gemmS: 128x128 tile, BK=64, 4 waves, 32 KB LDS ============
template<int NY, int EPI>
__device__ __forceinline__ void gemmS_body(
    const unsigned short* __restrict__ Ab, const unsigned short* __restrict__ Bw,
    const float* __restrict__ bias, unsigned short* __restrict__ outb, int K) {
  __shared__ unsigned short As[128 * 64];
  __shared__ unsigned short Bs[128 * 64];
  const int N = NY * 128;
  const int tid = threadIdx.x;
  const int w = tid >> 6, l = tid & 63;
  const int wrow = w >> 1, wcol = w & 1;
  const int nwg = gridDim.x;
  const int id = blockIdx.x;
  const int lid = (id & 7) * (nwg >> 3) + (id >> 3);
  const int mi = lid / NY, ni = lid - mi * NY;
  const int m0 = mi * 128, n0 = ni * 128;
  const int lr = l & 15, lh = l >> 4;
  f32x4 acc[4][4];
  #pragma unroll
  for (int m = 0; m < 4; ++m)
    #pragma unroll
    for (int n = 0; n < 4; ++n) acc[m][n] = (f32x4)0.f;
  const int rl7 = lr & 7;
  int aoff[4], boff[4];
  #pragma unroll
  for (int m = 0; m < 4; ++m)
    aoff[m] = (wrow * 64 + m * 16 + lr) * 128 + ((lh ^ rl7) << 4);
  #pragma unroll
  for (int n = 0; n < 4; ++n)
    boff[n] = (wcol * 64 + n * 16 + lr) * 128 + ((lh ^ rl7) << 4);
  const int srow8 = l >> 3;
  const int gch = (l & 7) ^ srow8;

  for (int k0 = 0; k0 < K; k0 += 64) {
    __syncthreads();
    #pragma unroll
    for (int c = 0; c < 4; ++c) {
      const int slot = c * 4 + w;
      const int R = slot * 8 + srow8;
      gload16(Ab + (long)(m0 + R) * K + k0 + gch * 8, (char*)As + slot * 1024);
      gload16(Bw + (long)(n0 + R) * K + k0 + gch * 8, (char*)Bs + slot * 1024);
    }
    __syncthreads();
    {
      bf16x8 a[4], b[4];
      #pragma unroll
      for (int m = 0; m < 4; ++m) a[m] = *(const bf16x8*)((const char*)As + aoff[m]);
      #pragma unroll
      for (int n = 0; n < 4; ++n) b[n] = *(const bf16x8*)((const char*)Bs + boff[n]);
      #pragma unroll
      for (int m = 0; m < 4; ++m)
        #pragma unroll
        for (int n = 0; n < 4; ++n)
          acc[m][n] = __builtin_amdgcn_mfma_f32_16x16x32_bf16(a[m], b[n], acc[m][n], 0, 0, 0);
    }
    {
      bf16x8 a[4], b[4];
      #pragma unroll
      for (int m = 0; m < 4; ++m) a[m] = *(const bf16x8*)((const char*)As + (aoff[m] ^ 64));
      #pragma unroll
      for (int n = 0; n < 4; ++n) b[n] = *(const bf16x8*)((const char*)Bs + (boff[n] ^ 64));
      #pragma unroll
      for (int m = 0; m < 4; ++m)
        #pragma unroll
        for (int n = 0; n < 4; ++n)
          acc[m][n] = __builtin_amdgcn_mfma_f32_16x16x32_bf16(a[m], b[n], acc[m][n], 0, 0, 0);
    }
  }

  float bv[4];
  #pragma unroll
  for (int n = 0; n < 4; ++n) bv[n] = bias[n0 + wcol * 64 + n * 16 + lr];
  #pragma unroll
  for (int m = 0; m < 4; ++m)
    #pragma unroll
    for (int reg = 0; reg < 4; ++reg) {
      const long row = m0 + wrow * 64 + m * 16 + lh * 4 + reg;
      #pragma unroll
      for (int n = 0; n < 4; ++n) {
        const int col = n0 + wcol * 64 + n * 16 + lr;
        float v = acc[m][n][reg] + bv[n];
        if constexpr (EPI == 3) v = v / (1.f + __expf(-v));
        outb[row * (long)N + col] = f2bf(v);
      }
    }
}

__global__ __launch_bounds__(256) void qkv_gemm(
    const unsigned short* __restrict__ A, const unsigned short* __restrict__ B,
    const float* __restrict__ bias, unsigned short* __restrict__ C) {
  gemmS_body<12, 2>(A, B, bias, C, 512);
}
__global__ __launch_bounds__(256) void mlp1_gemm(
    const unsigned short* __restrict__ A, const unsigned short* __restrict__ B,
    const float* __restrict__ bias, unsigned short* __restrict__ C) {
  gemmS_body<16, 3>(A, B, bias, C, 512);
}
__global__ __launch_bounds__(256) void mlp2_gemm(
    const unsigned short* __restrict__ A, const unsigned short* __restrict__ B,
    const float* __restrict__ bias, unsigned short* __restrict__ C) {
  gemmS_body<4, 2>(A, B, bias, C, 2048);
}

// ============ projf: 128x512 proj + fused RMS-norm1 + rolled residual ========
__global__ __launch_bounds__(512) void projf_gemm(
    const unsigned short* __restrict__ Ab, const unsigned short* __restrict__ Bw,
    const float* __restrict__ bias, const float* __restrict__ resid,
    const float* __restrict__ nw, float* __restrict__ outf,
    unsigned short* __restrict__ x1b) {
  const int K = 512;
  __shared__ unsigned short As[128 * 32];
  __shared__ unsigned short Bs[512 * 32];
  __shared__ float rsum[128][4];
  __shared__ float rinv[128];
  const int tid = threadIdx.x;
  const int ww = tid >> 6, l = tid & 63;
  const int wrow = ww >> 2, wcol = ww & 3;
  const int nwg = gridDim.x;
  const int id = blockIdx.x;
  const int lid = (id & 7) * (nwg >> 3) + (id >> 3);
  const int m0 = lid * 128;
  const int lr = l & 15, lh = l >> 4;
  f32x4 acc[4][8];
  #pragma unroll
  for (int m = 0; m < 4; ++m)
    #pragma unroll
    for (int n = 0; n < 8; ++n) acc[m][n] = (f32x4)0.f;
  const int fsw = (lr >> 1) & 3;
  int aoff[4], boff[8];
  #pragma unroll
  for (int m = 0; m < 4; ++m)
    aoff[m] = (wrow * 64 + m * 16 + lr) * 64 + ((lh ^ fsw) << 4);
  #pragma unroll
  for (int n = 0; n < 8; ++n)
    boff[n] = (wcol * 128 + n * 16 + lr) * 64 + ((lh ^ fsw) << 4);
  const int srow = l >> 2;
  const int schunk = (l & 3) ^ ((srow >> 1) & 3);

  for (int k0 = 0; k0 < K; k0 += 32) {
    __syncthreads();
    gload16(Ab + (long)(m0 + ww * 16 + srow) * K + k0 + schunk * 8, (char*)As + ww * 1024);
    #pragma unroll
    for (int c = 0; c < 4; ++c)
      gload16(Bw + (long)(c * 128 + ww * 16 + srow) * K + k0 + schunk * 8,
              (char*)Bs + c * 8192 + ww * 1024);
    __syncthreads();
    bf16x8 a[4], b[8];
    #pragma unroll
    for (int m = 0; m < 4; ++m) a[m] = *(const bf16x8*)((const char*)As + aoff[m]);
    #pragma unroll
    for (int n = 0; n < 8; ++n) b[n] = *(const bf16x8*)((const char*)Bs + boff[n]);
    #pragma unroll
    for (int m = 0; m < 4; ++m)
      #pragma unroll
      for (int n = 0; n < 8; ++n)
        acc[m][n] = __builtin_amdgcn_mfma_f32_16x16x32_bf16(a[m], b[n], acc[m][n], 0, 0, 0);
  }

  float bv[8], nwv[8];
  #pragma unroll
  for (int n = 0; n < 8; ++n) {
    const int col = wcol * 128 + n * 16 + lr;
    bv[n] = bias[col];
    nwv[n] = nw[col];
  }
  float part[4][4];
  #pragma unroll
  for (int m = 0; m < 4; ++m)
    #pragma unroll
    for (int reg = 0; reg < 4; ++reg) {
      float s = 0.f;
      #pragma unroll
      for (int n = 0; n < 8; ++n) {
        float v = acc[m][n][reg] + bv[n];
        s += v * v;
      }
      part[m][reg] = s;
    }
  #pragma unroll
  for (int off = 1; off < 16; off <<= 1)
    #pragma unroll
    for (int m = 0; m < 4; ++m)
      #pragma unroll
      for (int reg = 0; reg < 4; ++reg)
        part[m][reg] += __shfl_xor(part[m][reg], off);
  if (lr == 0) {
    #pragma unroll
    for (int m = 0; m < 4; ++m)
      #pragma unroll
      for (int reg = 0; reg < 4; ++reg)
        rsum[wrow * 64 + m * 16 + lh * 4 + reg][wcol] = part[m][reg];
  }
  __syncthreads();
  if (tid < 128) {
    float s = rsum[tid][0] + rsum[tid][1] + rsum[tid][2] + rsum[tid][3];
    rinv[tid] = SQRT_C * rsqrtf(s * (1.f / 512.f) + 1e-8f);
  }
  __syncthreads();
  #pragma unroll
  for (int m = 0; m < 4; ++m)
    #pragma unroll
    for (int reg = 0; reg < 4; ++reg) {
      const int rl = wrow * 64 + m * 16 + lh * 4 + reg;
      const long grow = m0 + rl;
      const float inv = rinv[rl];
      const long orow = (grow & ~(long)LMASK) | (((grow & LMASK) + 64) & LMASK);
      #pragma unroll
      for (int n = 0; n < 8; ++n) {
        const int col = wcol * 128 + n * 16 + lr;
        float v = acc[m][n][reg] + bv[n];
        float o = resid[orow * 512 + col] + v * inv * nwv[n];
        outf[orow * 512 + col] = o;
        x1b[orow * 512 + col] = f2bf(o);
      }
    }
}

// ---- addnorm2: out[r0+r] += rms(y[r])*nw (in place on d_out) ----
__global__ __launch_bounds__(128) void addnorm_final_k(const unsigned short* __restrict__ y,
    const float* __restrict__ nw, float* __restrict__ out, int r0) {
  const int r = blockIdx.x;
  const int tid = threadIdx.x;
  us4 u = *(const us4*)(y + (long)r * 512 + tid * 4);
  float v0 = bf2f(u[0]), v1 = bf2f(u[1]), v2 = bf2f(u[2]), v3 = bf2f(u[3]);
  float ss = v0 * v0 + v1 * v1 + v2 * v2 + v3 * v3;
  #pragma unroll
  for (int o = 1; o < 64; o <<= 1) ss += __shfl_xor(ss, o);
  __shared__ float tot[2];
  if ((tid & 63) == 0) tot[tid >> 6] = ss;
  __syncthreads();
  const float inv = SQRT_C * rsqrtf((tot[0] + tot[1]) * (1.f / 512.f) + 1e-8f);
  const long base = (long)(r0 + r) * 512 + tid * 4;
  float4 wv = *(const float4*)(nw + tid * 4);
  float4 xv = *(const float4*)(out + base);
  float4 o4;
  o4.x = xv.x + v0 * inv * wv.x;
  o4.y = xv.y + v1 * inv * wv.y;
  o4.z = xv.z + v2 * inv * wv.z;
  o4.w = xv.w + v3 * inv * wv.w;
  *(float4*)(out + base) = o4;
}

// ---------------- attention via MFMA: one block per (head, window) ----------------
// LDS overlap: ps (34.8 KB) reuses qs+ks region (dead after QK^T) -> 45.6 KB
// total -> 3 blocks/CU (was 60.5 KB / 2 blocks).
__global__ __launch_bounds__(256, 3) void attn_k(const unsigned short* __restrict__ qkv,
    const float* __restrict__ logit_scale, const float* __restrict__ sig_tbl,
    unsigned short* __restrict__ attnout) {
  __shared__ __align__(16) char smem[43520];
  unsigned short* vt = (unsigned short*)smem;             // [0, 8704)
  unsigned short* qs = (unsigned short*)(smem + 8704);    // [8704, 16896)
  unsigned short* ks = (unsigned short*)(smem + 16896);   // [16896, 25088)
  unsigned short* ps = (unsigned short*)(smem + 8704);    // [8704, 43520) reuse
  __shared__ float qinv[128], kinv[128], lbias[256];
  const int h = blockIdx.x, w = blockIdx.y;
  const int tid = threadIdx.x;
  const int wv = tid >> 6, l = tid & 63;
  const int lr = l & 15, quad = l >> 4;

  {
    const int srow = l >> 2;
    const int cs = (l & 3) ^ ((srow >> 1) & 3);
    #pragma unroll
    for (int rnd = 0; rnd < 2; ++rnd) {
      const int row = wv * 32 + rnd * 16 + srow;
      const long gb = (long)(w * 128 + row) * 1536 + h * 32 + cs * 8;
      gload16(qkv + gb, (char*)qs + (wv * 32 + rnd * 16) * 64);
      gload16(qkv + gb + 512, (char*)ks + (wv * 32 + rnd * 16) * 64);
    }
  }
  #pragma unroll
  for (int rnd = 0; rnd < 2; ++rnd) {
    const int j = wv * 32 + rnd * 16 + (l >> 2);
    const int d0 = (l & 3) * 8;
    us8 uv = *(const us8*)(qkv + (long)(w * 128 + j) * 1536 + h * 32 + 1024 + d0);
    #pragma unroll
    for (int e = 0; e < 8; ++e) vt[(d0 + e) * 136 + j] = uv[e];
  }
  if (tid < 255) lbias[tid] = sig_tbl[tid * 16 + h];
  __syncthreads();

  const float scale = __expf(fminf(logit_scale[h], LOGIT_MAXV));
  {
    const int r = tid >> 1, cp = tid & 1;
    const int sw = (r >> 1) & 3;
    float sq = 0.f, sk = 0.f;
    #pragma unroll
    for (int cc = 0; cc < 2; ++cc) {
      const int slot = (cp * 2 + cc) ^ sw;
      us8 uq = *(const us8*)(qs + r * 32 + slot * 8);
      us8 uk = *(const us8*)(ks + r * 32 + slot * 8);
      #pragma unroll
      for (int e = 0; e < 8; ++e) {
        float fq = bf2f(uq[e]), fk = bf2f(uk[e]);
        sq = fmaf(fq, fq, sq);
        sk = fmaf(fk, fk, sk);
      }
    }
    sq += __shfl_xor(sq, 1);
    sk += __shfl_xor(sk, 1);
    qinv[r] = scale / fmaxf(sqrtf(sq), 1e-12f);
    kinv[r] = 1.f / fmaxf(sqrtf(sk), 1e-12f);
  }
  __syncthreads();

  const int fsw = (lr >> 1) & 3;
  bf16x8 aq[2];
  #pragma unroll
  for (int mt = 0; mt < 2; ++mt)
    aq[mt] = *(const bf16x8*)((const char*)qs + (wv * 32 + mt * 16 + lr) * 64 + ((quad ^ fsw) << 4));
  f32x4 s[2][8];
  #pragma unroll
  for (int nt = 0; nt < 8; ++nt) {
    bf16x8 bk = *(const bf16x8*)((const char*)ks + (nt * 16 + lr) * 64 + ((quad ^ fsw) << 4));
    #pragma unroll
    for (int mt = 0; mt < 2; ++mt)
      s[mt][nt] = __builtin_amdgcn_mfma_f32_16x16x32_bf16(aq[mt], bk, (f32x4)0.f, 0, 0, 0);
  }
  // qs/ks fragments fully consumed into registers -> safe to overwrite with ps
  __syncthreads();

  float kv8[8];
  #pragma unroll
  for (int nt = 0; nt < 8; ++nt) kv8[nt] = kinv[nt * 16 + lr];
  const bool lastwin = ((w & 127) == 127);
  const bool ihalf = (wv < 2);
  float sum[2][4];
  #pragma unroll
  for (int mt = 0; mt < 2; ++mt) {
    #pragma unroll
    for (int reg = 0; reg < 4; ++reg) {
      const int row = wv * 32 + mt * 16 + quad * 4 + reg;
      const float qv = qinv[row];
      const int bb = row + 127 - lr;
      float m = -1e30f;
      #pragma unroll
      for (int nt = 0; nt < 8; ++nt) {
        float v = s[mt][nt][reg] * qv * kv8[nt] + lbias[bb - nt * 16];
        if (lastwin && (ihalf != (nt < 4))) v -= 100.f;
        s[mt][nt][reg] = v;
        m = fmaxf(m, v);
      }
      m = fmaxf(m, __shfl_xor(m, 1));
      m = fmaxf(m, __shfl_xor(m, 2));
      m = fmaxf(m, __shfl_xor(m, 4));
      m = fmaxf(m, __shfl_xor(m, 8));
      float sm = 0.f;
      #pragma unroll
      for (int nt = 0; nt < 8; ++nt) {
        float p = __expf(s[mt][nt][reg] - m);
        s[mt][nt][reg] = p;
        sm += p;
      }
      sm += __shfl_xor(sm, 1);
      sm += __shfl_xor(sm, 2);
      sm += __shfl_xor(sm, 4);
      sm += __shfl_xor(sm, 8);
      sum[mt][reg] = sm;
      #pragma unroll
      for (int nt = 0; nt < 8; ++nt)
        ps[row * 136 + nt * 16 + lr] = f2bf(s[mt][nt][reg]);
    }
  }
  __syncthreads();

  f32x4 o[2][2];
  #pragma unroll
  for (int mt = 0; mt < 2; ++mt)
    #pragma unroll
    for (int nt = 0; nt < 2; ++nt) o[mt][nt] = (f32x4)0.f;
  #pragma unroll
  for (int kt = 0; kt < 4; ++kt) {
    bf16x8 pa[2], vb[2];
    #pragma unroll
    for (int mt = 0; mt < 2; ++mt)
      pa[mt] = *(const bf16x8*)((const char*)ps + (wv * 32 + mt * 16 + lr) * 272 + (kt * 4 + quad) * 16);
    #pragma unroll
    for (int nt = 0; nt < 2; ++nt)
      vb[nt] = *(const bf16x8*)((const char*)vt + (nt * 16 + lr) * 272 + (kt * 4 + quad) * 16);
    #pragma unroll
    for (int mt = 0; mt < 2; ++mt)
      #pragma unroll
      for (int nt = 0; nt < 2; ++nt)
        o[mt][nt] = __builtin_amdgcn_mfma_f32_16x16x32_bf16(pa[mt], vb[nt], o[mt][nt], 0, 0, 0);
  }
  #pragma unroll
  for (int mt = 0; mt < 2; ++mt) {
    #pragma unroll
    for (int reg = 0; reg < 4; ++reg) {
      const int row = wv * 32 + mt * 16 + quad * 4 + reg;
      const float si = 1.f / sum[mt][reg];
      const long ob = (long)(w * 128 + row) * 512 + h * 32;
      attnout[ob + lr]      = f2bf(o[mt][0][reg] * si);
      attnout[ob + 16 + lr] = f2bf(o[mt][1][reg] * si);
    }
  }
}

// ---------------- launch ----------------
extern "C" void kernel_launch(void* const* d_in, const int* in_sizes, int n_in,
                              void* d_out, int out_size, void* d_ws, size_t ws_size,
                              hipStream_t stream) {
  const float* x       = (const float*)d_in[0];
  const float* qkv_w   = (const float*)d_in[1];
  const float* q_bias  = (const float*)d_in[2];
  const float* v_bias  = (const float*)d_in[3];
  const float* lscale  = (const float*)d_in[4];
  const float* cpb_w1  = (const float*)d_in[5];
  const float* cpb_b1  = (const float*)d_in[6];
  const float* cpb_w2  = (const float*)d_in[7];
  const float* proj_w  = (const float*)d_in[8];
  const float* proj_b  = (const float*)d_in[9];
  const float* norm1_w = (const float*)d_in[10];
  const float* norm2_w = (const float*)d_in[11];
  const float* mlp_w1  = (const float*)d_in[12];
  const float* mlp_b1  = (const float*)d_in[13];
  const float* mlp_w2  = (const float*)d_in[14];
  const float* mlp_b2  = (const float*)d_in[15];
  float* outp = (float*)d_out;
  char* ws = (char*)d_ws;

  unsigned short* w1b     = (unsigned short*)(ws + 0);          // persist
  unsigned short* w2b     = (unsigned short*)(ws + 2097152);    // persist
  unsigned short* qkv_wb  = (unsigned short*)(ws + 4194304);    // persist
  unsigned short* proj_wb = (unsigned short*)(ws + 5767168);    // persist
  float*          sig_tbl = (float*)(ws + 6291456);             // persist
  float*          qkvb    = (float*)(ws + 6311936);             // persist
  unsigned short* xb      = (unsigned short*)(ws + 8388608);    // [8,40)   prep->qkv
  unsigned short* attnout = (unsigned short*)(ws + 8388608);    // [8,40)   attn->projf
  unsigned short* x1b     = (unsigned short*)(ws + 8388608);    // [8,40)   projf->mlp1
  unsigned short* qkvbuf  = (unsigned short*)(ws + 41943040);   // [40,136) qkv->attn
  unsigned short* mlp2y   = (unsigned short*)(ws + 41943040);   // [40,72)  mlp2h->addn2h
  unsigned short* h2buf   = (unsigned short*)(ws + 75497472);   // [72,136) mlp1h->mlp2h

  prep_k<<<9734, 256, 0, stream>>>(mlp_w1, mlp_w2, qkv_w, proj_w, q_bias, v_bias, x,
                                   w1b, w2b, qkv_wb, proj_wb, qkvb, xb);
  cpb_k<<<255, 256, 0, stream>>>(cpb_w1, cpb_b1, cpb_w2, sig_tbl);

  // qkv = xb @ qkv_w^T + qkvb
  qkv_gemm<<<3072, 256, 0, stream>>>(xb, qkv_wb, qkvb, qkvbuf);
  // attention
  attn_k<<<dim3(16, 256), 256, 0, stream>>>(qkvbuf, lscale, sig_tbl, attnout);
  // proj + fused RMS-norm1 + rolled residual -> outp f32, x1b bf16
  projf_gemm<<<256, 512, 0, stream>>>(attnout, proj_wb, proj_b, x, norm1_w, outp, x1b);
  // MLP in two 16K-row halves sharing h2buf (64 MB)
  for (int half = 0; half < 2; ++half) {
    const long r0 = (long)half * 16384;
    mlp1_gemm<<<2048, 256, 0, stream>>>(x1b + r0 * 512, w1b, mlp_b1, h2buf);
    mlp2_gemm<<<512, 256, 0, stream>>>(h2buf, w2b, mlp_b2, mlp2y);
    addnorm_final_k<<<16384, 128, 0, stream>>>(mlp2y, norm2_w, outp, (int)r0);
  }
}

// Round 15
// 406.144 us; speedup vs baseline: 1.1710x; 1.0911x over previous
//
#include <hip/hip_runtime.h>

typedef __attribute__((ext_vector_type(8))) unsigned short us8;
typedef __attribute__((ext_vector_type(4))) unsigned short us4;
typedef __attribute__((ext_vector_type(8))) short bf16x8;
typedef __attribute__((ext_vector_type(4))) float f32x4;

#define LMASK 16383
#define SQRT_C 22.627416997969522f
#define LOGIT_MAXV 4.605170185988091f

__device__ __forceinline__ float bf2f(unsigned short u) {
  unsigned int x = ((unsigned int)u) << 16;
  return __builtin_bit_cast(float, x);
}
__device__ __forceinline__ unsigned short f2bf(float f) {
  unsigned int x = __builtin_bit_cast(unsigned int, f);
  x = x + 0x7FFFu + ((x >> 16) & 1u);
  return (unsigned short)(x >> 16);
}
__device__ __forceinline__ void gload16(const void* g, void* lds) {
  __builtin_amdgcn_global_load_lds(
      (const __attribute__((address_space(1))) unsigned int*)g,
      (__attribute__((address_space(3))) unsigned int*)lds, 16, 0, 0);
}

// ---------------- merged prep kernel ----------------
__global__ void prep_k(const float* __restrict__ mlp_w1, const float* __restrict__ mlp_w2,
                       const float* __restrict__ qkv_w, const float* __restrict__ proj_w,
                       const float* __restrict__ qb, const float* __restrict__ vb,
                       const float* __restrict__ x,
                       unsigned short* __restrict__ w1b, unsigned short* __restrict__ w2b,
                       unsigned short* __restrict__ qkv_wb, unsigned short* __restrict__ proj_wb,
                       float* __restrict__ qkvb, unsigned short* __restrict__ xb) {
  const int b = blockIdx.x;
  const int tid = threadIdx.x;
  if (b < 1536) {
    const float* src;
    unsigned short* dst;
    int base;
    if (b < 512)       { src = mlp_w1; dst = w1b;    base = b; }
    else if (b < 1024) { src = mlp_w2; dst = w2b;    base = b - 512; }
    else if (b < 1408) { src = qkv_w;  dst = qkv_wb; base = b - 1024; }
    else               { src = proj_w; dst = proj_wb; base = b - 1408; }
    const long idx = (long)base * 256 + tid;
    const float* s = src + idx * 8;
    us8 u;
    #pragma unroll
    for (int e = 0; e < 8; ++e) u[e] = f2bf(s[e]);
    *(us8*)(dst + idx * 8) = u;
  } else if (b < 1542) {
    const int n = (b - 1536) * 256 + tid;
    float v = 0.f;
    if (n < 512) v = qb[n];
    else if (n >= 1024) v = vb[n - 1024];
    qkvb[n] = v;
  } else {
    long e = ((long)(b - 1542) * 256 + tid) * 8;
    long row = e >> 9;
    int col = (int)(e & 511);
    long src = ((row >> 14) << 14) | (((row & LMASK) + 64) & LMASK);
    const float* s = x + src * 512 + col;
    us8 u;
    #pragma unroll
    for (int ee = 0; ee < 8; ++ee) u[ee] = f2bf(s[ee]);
    *(us8*)(xb + e) = u;
  }
}

__global__ __launch_bounds__(256) void cpb_k(const float* __restrict__ w1,
    const float* __restrict__ b1, const float* __restrict__ w2,
    float* __restrict__ sig_tbl) {
  __shared__ float hbuf[512];
  const int i = blockIdx.x;
  const int tid = threadIdx.x;
  const float t = (float)(i - 127) * (8.f / 127.f);
  const float sgn = (t < 0.f) ? -1.f : 1.f;
  const float s = sgn * (log2f(fabsf(t) + 1.f) * (1.f / 3.f));
  hbuf[tid]       = fmaxf(s * w1[tid] + b1[tid], 0.f);
  hbuf[tid + 256] = fmaxf(s * w1[tid + 256] + b1[tid + 256], 0.f);
  __syncthreads();
  const int wv = tid >> 6, lane = tid & 63;
  for (int q = 0; q < 4; ++q) {
    const int n = wv * 4 + q;
    float part = 0.f;
    for (int c = lane; c < 512; c += 64) part += hbuf[c] * w2[n * 512 + c];
    #pragma unroll
    for (int o = 1; o < 64; o <<= 1) part += __shfl_xor(part, o);
    if (lane == 0) sig_tbl[i * 16 + n] = 16.f / (1.f + expf(-part));
  }
}

// ============ gemmS: 128x128 tile, BK=64, 4 waves, 32 KB LDS ============
template<int NY, int EPI>
__device__ __forceinline__ void gemmS_body(
    const unsigned short* __restrict__ Ab, const unsigned short* __restrict__ Bw,
    const float* __restrict__ bias, unsigned short* __restrict__ outb, int K) {
  __shared__ unsigned short As[128 * 64];
  __shared__ unsigned short Bs[128 * 64];
  const int N = NY * 128;
  const int tid = threadIdx.x;
  const int w = tid >> 6, l = tid & 63;
  const int wrow = w >> 1, wcol = w & 1;
  const int nwg = gridDim.x;
  const int id = blockIdx.x;
  const int lid = (id & 7) * (nwg >> 3) + (id >> 3);
  const int mi = lid / NY, ni = lid - mi * NY;
  const int m0 = mi * 128, n0 = ni * 128;
  const int lr = l & 15, lh = l >> 4;
  f32x4 acc[4][4];
  #pragma unroll
  for (int m = 0; m < 4; ++m)
    #pragma unroll
    for (int n = 0; n < 4; ++n) acc[m][n] = (f32x4)0.f;
  const int rl7 = lr & 7;
  int aoff[4], boff[4];
  #pragma unroll
  for (int m = 0; m < 4; ++m)
    aoff[m] = (wrow * 64 + m * 16 + lr) * 128 + ((lh ^ rl7) << 4);
  #pragma unroll
  for (int n = 0; n < 4; ++n)
    boff[n] = (wcol * 64 + n * 16 + lr) * 128 + ((lh ^ rl7) << 4);
  const int srow8 = l >> 3;
  const int gch = (l & 7) ^ srow8;

  for (int k0 = 0; k0 < K; k0 += 64) {
    __syncthreads();
    #pragma unroll
    for (int c = 0; c < 4; ++c) {
      const int slot = c * 4 + w;
      const int R = slot * 8 + srow8;
      gload16(Ab + (long)(m0 + R) * K + k0 + gch * 8, (char*)As + slot * 1024);
      gload16(Bw + (long)(n0 + R) * K + k0 + gch * 8, (char*)Bs + slot * 1024);
    }
    __syncthreads();
    {
      bf16x8 a[4], b[4];
      #pragma unroll
      for (int m = 0; m < 4; ++m) a[m] = *(const bf16x8*)((const char*)As + aoff[m]);
      #pragma unroll
      for (int n = 0; n < 4; ++n) b[n] = *(const bf16x8*)((const char*)Bs + boff[n]);
      #pragma unroll
      for (int m = 0; m < 4; ++m)
        #pragma unroll
        for (int n = 0; n < 4; ++n)
          acc[m][n] = __builtin_amdgcn_mfma_f32_16x16x32_bf16(a[m], b[n], acc[m][n], 0, 0, 0);
    }
    {
      bf16x8 a[4], b[4];
      #pragma unroll
      for (int m = 0; m < 4; ++m) a[m] = *(const bf16x8*)((const char*)As + (aoff[m] ^ 64));
      #pragma unroll
      for (int n = 0; n < 4; ++n) b[n] = *(const bf16x8*)((const char*)Bs + (boff[n] ^ 64));
      #pragma unroll
      for (int m = 0; m < 4; ++m)
        #pragma unroll
        for (int n = 0; n < 4; ++n)
          acc[m][n] = __builtin_amdgcn_mfma_f32_16x16x32_bf16(a[m], b[n], acc[m][n], 0, 0, 0);
    }
  }

  float bv[4];
  #pragma unroll
  for (int n = 0; n < 4; ++n) bv[n] = bias[n0 + wcol * 64 + n * 16 + lr];
  #pragma unroll
  for (int m = 0; m < 4; ++m)
    #pragma unroll
    for (int reg = 0; reg < 4; ++reg) {
      const long row = m0 + wrow * 64 + m * 16 + lh * 4 + reg;
      #pragma unroll
      for (int n = 0; n < 4; ++n) {
        const int col = n0 + wcol * 64 + n * 16 + lr;
        float v = acc[m][n][reg] + bv[n];
        if constexpr (EPI == 3) v = v / (1.f + __expf(-v));
        outb[row * (long)N + col] = f2bf(v);
      }
    }
}

__global__ __launch_bounds__(256) void qkv_gemm(
    const unsigned short* __restrict__ A, const unsigned short* __restrict__ B,
    const float* __restrict__ bias, unsigned short* __restrict__ C) {
  gemmS_body<12, 2>(A, B, bias, C, 512);
}
__global__ __launch_bounds__(256) void proj_gemm(
    const unsigned short* __restrict__ A, const unsigned short* __restrict__ B,
    const float* __restrict__ bias, unsigned short* __restrict__ C) {
  gemmS_body<4, 2>(A, B, bias, C, 512);
}
__global__ __launch_bounds__(256) void mlp1_gemm(
    const unsigned short* __restrict__ A, const unsigned short* __restrict__ B,
    const float* __restrict__ bias, unsigned short* __restrict__ C) {
  gemmS_body<16, 3>(A, B, bias, C, 512);
}
__global__ __launch_bounds__(256) void mlp2_gemm(
    const unsigned short* __restrict__ A, const unsigned short* __restrict__ B,
    const float* __restrict__ bias, unsigned short* __restrict__ C) {
  gemmS_body<4, 2>(A, B, bias, C, 2048);
}

// ---- addnorm1: x1b[dest] = bf16(x[dest] + rms(y[r])*nw), dest = roll(r) ----
// (x1 lives only in bf16: mlp1 input AND final residual base)
__global__ __launch_bounds__(128) void addnorm_roll_k(const unsigned short* __restrict__ y,
    const float* __restrict__ x, const float* __restrict__ nw,
    unsigned short* __restrict__ x1b) {
  const int r = blockIdx.x;
  const int tid = threadIdx.x;
  us4 u = *(const us4*)(y + (long)r * 512 + tid * 4);
  float v0 = bf2f(u[0]), v1 = bf2f(u[1]), v2 = bf2f(u[2]), v3 = bf2f(u[3]);
  float ss = v0 * v0 + v1 * v1 + v2 * v2 + v3 * v3;
  #pragma unroll
  for (int o = 1; o < 64; o <<= 1) ss += __shfl_xor(ss, o);
  __shared__ float tot[2];
  if ((tid & 63) == 0) tot[tid >> 6] = ss;
  __syncthreads();
  const float inv = SQRT_C * rsqrtf((tot[0] + tot[1]) * (1.f / 512.f) + 1e-8f);
  const long dest = ((long)(r >> 14) << 14) | (((r & LMASK) + 64) & LMASK);
  float4 wv = *(const float4*)(nw + tid * 4);
  float4 xv = *(const float4*)(x + dest * 512 + tid * 4);
  us4 ub;
  ub[0] = f2bf(xv.x + v0 * inv * wv.x);
  ub[1] = f2bf(xv.y + v1 * inv * wv.y);
  ub[2] = f2bf(xv.z + v2 * inv * wv.z);
  ub[3] = f2bf(xv.w + v3 * inv * wv.w);
  *(us4*)(x1b + dest * 512 + tid * 4) = ub;
}

// ---- addnorm2: out[r0+r] = x1b[r0+r] + rms(y[r])*nw (single write, no RMW) ----
__global__ __launch_bounds__(128) void addnorm_final_k(const unsigned short* __restrict__ y,
    const unsigned short* __restrict__ x1b, const float* __restrict__ nw,
    float* __restrict__ out, int r0) {
  const int r = blockIdx.x;
  const int tid = threadIdx.x;
  us4 u = *(const us4*)(y + (long)r * 512 + tid * 4);
  float v0 = bf2f(u[0]), v1 = bf2f(u[1]), v2 = bf2f(u[2]), v3 = bf2f(u[3]);
  float ss = v0 * v0 + v1 * v1 + v2 * v2 + v3 * v3;
  #pragma unroll
  for (int o = 1; o < 64; o <<= 1) ss += __shfl_xor(ss, o);
  __shared__ float tot[2];
  if ((tid & 63) == 0) tot[tid >> 6] = ss;
  __syncthreads();
  const float inv = SQRT_C * rsqrtf((tot[0] + tot[1]) * (1.f / 512.f) + 1e-8f);
  const long base = (long)(r0 + r) * 512 + tid * 4;
  float4 wv = *(const float4*)(nw + tid * 4);
  us4 xv = *(const us4*)(x1b + base);
  float4 o4;
  o4.x = bf2f(xv[0]) + v0 * inv * wv.x;
  o4.y = bf2f(xv[1]) + v1 * inv * wv.y;
  o4.z = bf2f(xv[2]) + v2 * inv * wv.z;
  o4.w = bf2f(xv[3]) + v3 * inv * wv.w;
  *(float4*)(out + base) = o4;
}

// ---------------- attention via MFMA: one block per (head, window) ----------------
// LDS overlap: ps reuses qs+ks region (dead after QK^T) -> 45.6 KB -> 3 blocks/CU.
__global__ __launch_bounds__(256, 3) void attn_k(const unsigned short* __restrict__ qkv,
    const float* __restrict__ logit_scale, const float* __restrict__ sig_tbl,
    unsigned short* __restrict__ attnout) {
  __shared__ __align__(16) char smem[43520];
  unsigned short* vt = (unsigned short*)smem;             // [0, 8704)
  unsigned short* qs = (unsigned short*)(smem + 8704);    // [8704, 16896)
  unsigned short* ks = (unsigned short*)(smem + 16896);   // [16896, 25088)
  unsigned short* ps = (unsigned short*)(smem + 8704);    // [8704, 43520) reuse
  __shared__ float qinv[128], kinv[128], lbias[256];
  const int h = blockIdx.x, w = blockIdx.y;
  const int tid = threadIdx.x;
  const int wv = tid >> 6, l = tid & 63;
  const int lr = l & 15, quad = l >> 4;

  {
    const int srow = l >> 2;
    const int cs = (l & 3) ^ ((srow >> 1) & 3);
    #pragma unroll
    for (int rnd = 0; rnd < 2; ++rnd) {
      const int row = wv * 32 + rnd * 16 + srow;
      const long gb = (long)(w * 128 + row) * 1536 + h * 32 + cs * 8;
      gload16(qkv + gb, (char*)qs + (wv * 32 + rnd * 16) * 64);
      gload16(qkv + gb + 512, (char*)ks + (wv * 32 + rnd * 16) * 64);
    }
  }
  #pragma unroll
  for (int rnd = 0; rnd < 2; ++rnd) {
    const int j = wv * 32 + rnd * 16 + (l >> 2);
    const int d0 = (l & 3) * 8;
    us8 uv = *(const us8*)(qkv + (long)(w * 128 + j) * 1536 + h * 32 + 1024 + d0);
    #pragma unroll
    for (int e = 0; e < 8; ++e) vt[(d0 + e) * 136 + j] = uv[e];
  }
  if (tid < 255) lbias[tid] = sig_tbl[tid * 16 + h];
  __syncthreads();

  const float scale = __expf(fminf(logit_scale[h], LOGIT_MAXV));
  {
    const int r = tid >> 1, cp = tid & 1;
    const int sw = (r >> 1) & 3;
    float sq = 0.f, sk = 0.f;
    #pragma unroll
    for (int cc = 0; cc < 2; ++cc) {
      const int slot = (cp * 2 + cc) ^ sw;
      us8 uq = *(const us8*)(qs + r * 32 + slot * 8);
      us8 uk = *(const us8*)(ks + r * 32 + slot * 8);
      #pragma unroll
      for (int e = 0; e < 8; ++e) {
        float fq = bf2f(uq[e]), fk = bf2f(uk[e]);
        sq = fmaf(fq, fq, sq);
        sk = fmaf(fk, fk, sk);
      }
    }
    sq += __shfl_xor(sq, 1);
    sk += __shfl_xor(sk, 1);
    qinv[r] = scale / fmaxf(sqrtf(sq), 1e-12f);
    kinv[r] = 1.f / fmaxf(sqrtf(sk), 1e-12f);
  }
  __syncthreads();

  const int fsw = (lr >> 1) & 3;
  bf16x8 aq[2];
  #pragma unroll
  for (int mt = 0; mt < 2; ++mt)
    aq[mt] = *(const bf16x8*)((const char*)qs + (wv * 32 + mt * 16 + lr) * 64 + ((quad ^ fsw) << 4));
  f32x4 s[2][8];
  #pragma unroll
  for (int nt = 0; nt < 8; ++nt) {
    bf16x8 bk = *(const bf16x8*)((const char*)ks + (nt * 16 + lr) * 64 + ((quad ^ fsw) << 4));
    #pragma unroll
    for (int mt = 0; mt < 2; ++mt)
      s[mt][nt] = __builtin_amdgcn_mfma_f32_16x16x32_bf16(aq[mt], bk, (f32x4)0.f, 0, 0, 0);
  }
  __syncthreads();

  float kv8[8];
  #pragma unroll
  for (int nt = 0; nt < 8; ++nt) kv8[nt] = kinv[nt * 16 + lr];
  const bool lastwin = ((w & 127) == 127);
  const bool ihalf = (wv < 2);
  float sum[2][4];
  #pragma unroll
  for (int mt = 0; mt < 2; ++mt) {
    #pragma unroll
    for (int reg = 0; reg < 4; ++reg) {
      const int row = wv * 32 + mt * 16 + quad * 4 + reg;
      const float qv = qinv[row];
      const int bb = row + 127 - lr;
      float m = -1e30f;
      #pragma unroll
      for (int nt = 0; nt < 8; ++nt) {
        float v = s[mt][nt][reg] * qv * kv8[nt] + lbias[bb - nt * 16];
        if (lastwin && (ihalf != (nt < 4))) v -= 100.f;
        s[mt][nt][reg] = v;
        m = fmaxf(m, v);
      }
      m = fmaxf(m, __shfl_xor(m, 1));
      m = fmaxf(m, __shfl_xor(m, 2));
      m = fmaxf(m, __shfl_xor(m, 4));
      m = fmaxf(m, __shfl_xor(m, 8));
      float sm = 0.f;
      #pragma unroll
      for (int nt = 0; nt < 8; ++nt) {
        float p = __expf(s[mt][nt][reg] - m);
        s[mt][nt][reg] = p;
        sm += p;
      }
      sm += __shfl_xor(sm, 1);
      sm += __shfl_xor(sm, 2);
      sm += __shfl_xor(sm, 4);
      sm += __shfl_xor(sm, 8);
      sum[mt][reg] = sm;
      #pragma unroll
      for (int nt = 0; nt < 8; ++nt)
        ps[row * 136 + nt * 16 + lr] = f2bf(s[mt][nt][reg]);
    }
  }
  __syncthreads();

  f32x4 o[2][2];
  #pragma unroll
  for (int mt = 0; mt < 2; ++mt)
    #pragma unroll
    for (int nt = 0; nt < 2; ++nt) o[mt][nt] = (f32x4)0.f;
  #pragma unroll
  for (int kt = 0; kt < 4; ++kt) {
    bf16x8 pa[2], vb[2];
    #pragma unroll
    for (int mt = 0; mt < 2; ++mt)
      pa[mt] = *(const bf16x8*)((const char*)ps + (wv * 32 + mt * 16 + lr) * 272 + (kt * 4 + quad) * 16);
    #pragma unroll
    for (int nt = 0; nt < 2; ++nt)
      vb[nt] = *(const bf16x8*)((const char*)vt + (nt * 16 + lr) * 272 + (kt * 4 + quad) * 16);
    #pragma unroll
    for (int mt = 0; mt < 2; ++mt)
      #pragma unroll
      for (int nt = 0; nt < 2; ++nt)
        o[mt][nt] = __builtin_amdgcn_mfma_f32_16x16x32_bf16(pa[mt], vb[nt], o[mt][nt], 0, 0, 0);
  }
  #pragma unroll
  for (int mt = 0; mt < 2; ++mt) {
    #pragma unroll
    for (int reg = 0; reg < 4; ++reg) {
      const int row = wv * 32 + mt * 16 + quad * 4 + reg;
      const float si = 1.f / sum[mt][reg];
      const long ob = (long)(w * 128 + row) * 512 + h * 32;
      attnout[ob + lr]      = f2bf(o[mt][0][reg] * si);
      attnout[ob + 16 + lr] = f2bf(o[mt][1][reg] * si);
    }
  }
}

// ---------------- launch ----------------
extern "C" void kernel_launch(void* const* d_in, const int* in_sizes, int n_in,
                              void* d_out, int out_size, void* d_ws, size_t ws_size,
                              hipStream_t stream) {
  const float* x       = (const float*)d_in[0];
  const float* qkv_w   = (const float*)d_in[1];
  const float* q_bias  = (const float*)d_in[2];
  const float* v_bias  = (const float*)d_in[3];
  const float* lscale  = (const float*)d_in[4];
  const float* cpb_w1  = (const float*)d_in[5];
  const float* cpb_b1  = (const float*)d_in[6];
  const float* cpb_w2  = (const float*)d_in[7];
  const float* proj_w  = (const float*)d_in[8];
  const float* proj_b  = (const float*)d_in[9];
  const float* norm1_w = (const float*)d_in[10];
  const float* norm2_w = (const float*)d_in[11];
  const float* mlp_w1  = (const float*)d_in[12];
  const float* mlp_b1  = (const float*)d_in[13];
  const float* mlp_w2  = (const float*)d_in[14];
  const float* mlp_b2  = (const float*)d_in[15];
  float* outp = (float*)d_out;
  char* ws = (char*)d_ws;

  unsigned short* w1b     = (unsigned short*)(ws + 0);          // persist
  unsigned short* w2b     = (unsigned short*)(ws + 2097152);    // persist
  unsigned short* qkv_wb  = (unsigned short*)(ws + 4194304);    // persist
  unsigned short* proj_wb = (unsigned short*)(ws + 5767168);    // persist
  float*          sig_tbl = (float*)(ws + 6291456);             // persist
  float*          qkvb    = (float*)(ws + 6311936);             // persist
  unsigned short* xb      = (unsigned short*)(ws + 8388608);    // [8,40)   prep->qkv
  unsigned short* attnout = (unsigned short*)(ws + 8388608);    // [8,40)   attn->proj
  unsigned short* x1b     = (unsigned short*)(ws + 8388608);    // [8,40)   roll->mlp1,addn2
  unsigned short* qkvbuf  = (unsigned short*)(ws + 41943040);   // [40,136) qkv->attn
  unsigned short* projy   = (unsigned short*)(ws + 41943040);   // [40,72)  proj->roll
  unsigned short* mlp2y   = (unsigned short*)(ws + 41943040);   // [40,72)  mlp2h->addn2h
  unsigned short* h2buf   = (unsigned short*)(ws + 75497472);   // [72,136) mlp1h->mlp2h

  prep_k<<<9734, 256, 0, stream>>>(mlp_w1, mlp_w2, qkv_w, proj_w, q_bias, v_bias, x,
                                   w1b, w2b, qkv_wb, proj_wb, qkvb, xb);
  cpb_k<<<255, 256, 0, stream>>>(cpb_w1, cpb_b1, cpb_w2, sig_tbl);

  // qkv = xb @ qkv_w^T + qkvb
  qkv_gemm<<<3072, 256, 0, stream>>>(xb, qkv_wb, qkvb, qkvbuf);
  // attention
  attn_k<<<dim3(16, 256), 256, 0, stream>>>(qkvbuf, lscale, sig_tbl, attnout);
  // proj (plain bf16 out, BK=64 gemmS) + rolled addnorm -> x1b bf16 only
  proj_gemm<<<1024, 256, 0, stream>>>(attnout, proj_wb, proj_b, projy);
  addnorm_roll_k<<<32768, 128, 0, stream>>>(projy, x, norm1_w, x1b);
  // MLP in two 16K-row halves sharing h2buf (64 MB)
  for (int half = 0; half < 2; ++half) {
    const long r0 = (long)half * 16384;
    mlp1_gemm<<<2048, 256, 0, stream>>>(x1b + r0 * 512, w1b, mlp_b1, h2buf);
    mlp2_gemm<<<512, 256, 0, stream>>>(h2buf, w2b, mlp_b2, mlp2y);
    addnorm_final_k<<<16384, 128, 0, stream>>>(mlp2y, x1b, norm2_w, outp, (int)r0);
  }
}